// Round 11
// baseline (485.868 us; speedup 1.0000x reference)
//
#include <hip/hip_runtime.h>

// ============================================================================
// Swin V2 block, round 11 = R10 + fused MLP (fc1+silu+fc2 in one kernel,
// hidden 64x768 tile never touches HBM: ~300MB traffic removed).
// R10 post-mortem: T14 won (458->422); qkv/fc1 90us, fc2 ~70us. hmid
// round-trip = 151MB write + 151MB read = biggest structural waste.
// mlp_fused: per 64-row block, 4 chunks of 192 hidden cols:
//   fc1 (K=192, w1 via R10 Bl staging) -> silu -> hidden chunk to LDS
//   (slot-permuted) -> fc2 partial (K=192, A from LDS, B=w2p frags direct
//   from global/L2). LDS 66.5KB dynamic -> 2 blocks/CU.
// MFMA layout (HW-verified): A row=lane%16, slot=lane/16*8..+7;
// C/D col=lane%16, row=4*(lane/16)+reg. slot(k)=8*((k%16)/4)+4*(k/16)+k%4.
// ============================================================================

typedef unsigned short ushort_t;
using f32x4  = __attribute__((ext_vector_type(4))) float;
using short8 = __attribute__((ext_vector_type(8))) short;

__device__ __forceinline__ ushort_t f2bf(float f) {
  union { float f; unsigned u; } v; v.f = f;
  unsigned r = v.u + 0x7fffu + ((v.u >> 16) & 1u);
  return (ushort_t)(r >> 16);
}
__device__ __forceinline__ float bf2f(ushort_t u) {
  union { unsigned u; float f; } v; v.u = ((unsigned)u) << 16;
  return v.f;
}

// windowed-token index m -> image row index (same map for gather and scatter)
__device__ __forceinline__ int img_pos(int m) {
  int win = m / 49, n = m - win * 49;
  int b = win >> 6, wi = win & 63;
  int nd = n / 7, nm = n - nd * 7;
  int hs = (wi >> 3) * 7 + nd;
  int ws = (wi & 7) * 7 + nm;
  int h = hs + 3; if (h >= 56) h -= 56;
  int w = ws + 3; if (w >= 56) w -= 56;
  return b * 3136 + h * 56 + w;
}

__device__ __forceinline__ int region3(int a) { return a < 49 ? 0 : (a < 53 ? 1 : 2); }

// ---------------------------------------------------------------------------
__global__ void cvt_kernel(const float* __restrict__ in, ushort_t* __restrict__ out, int n) {
  int i = blockIdx.x * 256 + threadIdx.x;
  if (i < n) out[i] = f2bf(in[i]);
}

// weight convert + k-permute within each 32-block of the K dim (for w2)
__global__ void cvt_perm_kernel(const float* __restrict__ in, ushort_t* __restrict__ out,
                                int n, int K) {
  int i = blockIdx.x * 256 + threadIdx.x;
  if (i >= n) return;
  int row = i / K, j = i - row * K;
  int k = j & 31;
  int s = (j & ~31) + (((k & 15) >> 2) << 3) + ((k >> 4) << 2) + (k & 3);
  out[row * K + s] = f2bf(in[i]);
}

// gather shifted-window rows + convert to bf16: xw[m][c] = bf16(x[img_pos(m)][c])
__global__ __launch_bounds__(256) void gather_cvt_kernel(
    const float* __restrict__ x, ushort_t* __restrict__ xw) {
  int i8 = blockIdx.x * 256 + threadIdx.x;      // 100352*24 tasks of 8 elems
  int m = i8 / 24, c8 = (i8 - m * 24) * 8;
  const float* p = x + (size_t)img_pos(m) * 192 + c8;
  float4 a = *(const float4*)p, b = *(const float4*)(p + 4);
  ushort_t* q = xw + (size_t)m * 192 + c8;
  *(ushort4*)q       = make_ushort4(f2bf(a.x), f2bf(a.y), f2bf(a.z), f2bf(a.w));
  *(ushort4*)(q + 4) = make_ushort4(f2bf(b.x), f2bf(b.y), f2bf(b.z), f2bf(b.w));
}

// ---------------------------------------------------------------------------
// CPB: tab_s[head][e] = 16*sigmoid( relu(REL_TABLE[e] @ w1.T + b1) @ w2.T )
__global__ __launch_bounds__(256) void cpb_kernel(
    const float* __restrict__ w1, const float* __restrict__ b1,
    const float* __restrict__ w2, float* __restrict__ tab_s) {
  int e = blockIdx.x;            // 0..168
  int t = threadIdx.x;           // 0..255
  int i = e / 13, j = e - 13 * (e / 13);
  auto cval = [](int a) -> float {
    float r = (a - 6) * (8.0f / 6.0f);
    float v = log2f(fabsf(r) + 1.f) * (1.f / 3.f);
    return r < 0.f ? -v : v;
  };
  float ci = cval(i), cj = cval(j);
  float h = fmaxf(ci * w1[2 * t] + cj * w1[2 * t + 1] + b1[t], 0.f);
  __shared__ float red[256];
  for (int head = 0; head < 6; ++head) {
    red[t] = h * w2[head * 256 + t];
    __syncthreads();
    for (int st = 128; st > 0; st >>= 1) {
      if (t < st) red[t] += red[t + st];
      __syncthreads();
    }
    if (t == 0) tab_s[head * 169 + e] = 16.f / (1.f + __expf(-red[0]));
    __syncthreads();
  }
}

// ---------------------------------------------------------------------------
// GEMM, tile 128(M) x 192(N), K-step 32, 4 waves (2x2 of 64x96), bf16 A.
// T14 async-split reg prefetch (R10, proven).
// MODE 0: qkv  MODE 1: fc1(silu)  MODE 2: proj  MODE 3: fp32 out
template<int KTOT, int MODE>
__global__ __launch_bounds__(256) void gemm_n192(
    const ushort_t* __restrict__ Ab, const ushort_t* __restrict__ W,
    const float* __restrict__ b0, const float* __restrict__ b1,
    ushort_t* out, float* outf, int NTOT) {
  __shared__ ushort_t Al[128][40];
  __shared__ ushort_t Bl[192][40];
  int t = threadIdx.x;
  int m0 = blockIdx.x * 128, n0 = blockIdx.y * 192;

  int arow = t >> 1, akoff = (t & 1) << 4;
  const ushort_t* Arowp = Ab + (size_t)(m0 + arow) * KTOT + akoff;
  int colA = akoff ? 4 : 0;

  int lane = t & 63, wid = t >> 6;
  int wm = wid >> 1, wn = wid & 1;
  int lr = lane & 15, lg = lane >> 4;

  int bn = t >> 2, cB = t & 3;
  const ushort_t* Browp = W + (size_t)(n0 + bn) * KTOT + (cB << 3);
  const ushort_t* Browp2 = W + (size_t)(n0 + 64 + bn) * KTOT + (cB << 3);
  const ushort_t* Browp3 = W + (size_t)(n0 + 128 + bn) * KTOT + (cB << 3);
  int colB = ((cB & 1) << 4) | ((cB >> 1) << 2);   // {0,16,4,20}

  f32x4 acc[4][6];
#pragma unroll
  for (int a = 0; a < 4; ++a)
#pragma unroll
    for (int b = 0; b < 6; ++b) acc[a][b] = (f32x4){0.f, 0.f, 0.f, 0.f};

  ushort4 a0, a1, a2, a3, bq0[2], bq1[2], bq2[2];
  auto LOADREGS = [&](int kt) {
    a0 = *(const ushort4*)(Arowp + kt + 0);
    a1 = *(const ushort4*)(Arowp + kt + 4);
    a2 = *(const ushort4*)(Arowp + kt + 8);
    a3 = *(const ushort4*)(Arowp + kt + 12);
    bq0[0] = *(const ushort4*)(Browp + kt);
    bq0[1] = *(const ushort4*)(Browp + kt + 4);
    bq1[0] = *(const ushort4*)(Browp2 + kt);
    bq1[1] = *(const ushort4*)(Browp2 + kt + 4);
    bq2[0] = *(const ushort4*)(Browp3 + kt);
    bq2[1] = *(const ushort4*)(Browp3 + kt + 4);
  };

  const int NT = KTOT / 32;
  LOADREGS(0);
  for (int it = 0; it < NT; ++it) {
    ushort_t* Ar = &Al[arow][0];
    *(ushort4*)(Ar + colA +  0) = a0;
    *(ushort4*)(Ar + colA +  8) = a1;
    *(ushort4*)(Ar + colA + 16) = a2;
    *(ushort4*)(Ar + colA + 24) = a3;
    ushort_t* Br0 = &Bl[bn][0];
    *(ushort4*)(Br0 + colB + 0) = bq0[0];
    *(ushort4*)(Br0 + colB + 8) = bq0[1];
    ushort_t* Br1 = &Bl[64 + bn][0];
    *(ushort4*)(Br1 + colB + 0) = bq1[0];
    *(ushort4*)(Br1 + colB + 8) = bq1[1];
    ushort_t* Br2 = &Bl[128 + bn][0];
    *(ushort4*)(Br2 + colB + 0) = bq2[0];
    *(ushort4*)(Br2 + colB + 8) = bq2[1];
    __syncthreads();
    if (it + 1 < NT) LOADREGS((it + 1) * 32);   // in flight during MFMAs
    short8 af[4], bfv[6];
#pragma unroll
    for (int fm = 0; fm < 4; ++fm)
      af[fm] = *(const short8*)&Al[wm * 64 + fm * 16 + lr][lg * 8];
#pragma unroll
    for (int fn = 0; fn < 6; ++fn)
      bfv[fn] = *(const short8*)&Bl[wn * 96 + fn * 16 + lr][lg * 8];
#pragma unroll
    for (int fm = 0; fm < 4; ++fm)
#pragma unroll
      for (int fn = 0; fn < 6; ++fn)
        acc[fm][fn] = __builtin_amdgcn_mfma_f32_16x16x32_bf16(af[fm], bfv[fn], acc[fm][fn], 0, 0, 0);
    if (it + 1 < NT) __syncthreads();
  }
#pragma unroll
  for (int fm = 0; fm < 4; ++fm) {
#pragma unroll
    for (int fn = 0; fn < 6; ++fn) {
      int col = n0 + wn * 96 + fn * 16 + lr;
      float bias;
      if (MODE == 0) bias = (col < 192) ? b0[col] : ((col < 384) ? 0.f : b1[col - 384]);
      else           bias = b0[col];
#pragma unroll
      for (int r = 0; r < 4; ++r) {
        int row = m0 + wm * 64 + fm * 16 + lg * 4 + r;
        float v = acc[fm][fn][r] + bias;
        if (MODE == 1) v = v / (1.f + __expf(-v));   // silu
        if (MODE == 3) outf[(size_t)row * NTOT + col] = v;
        else           out[(size_t)row * NTOT + col] = f2bf(v);
      }
    }
  }
}

// ---------------------------------------------------------------------------
// Fused MLP: 64-row tile, 4 waves (2x2 of 32rows x 96cols).
// Per chunk c (192 hidden cols): fc1 (K=192, A from A_x1 LDS, B=w1 via Bl
// staging) + silu -> hidc LDS (slot-permuted) -> fc2 partial (K=192, A from
// hidc, B=w2p frags direct from global). Out = pre-LN fp32 -> d_out.
// dynamic LDS: A_x1[64][200] | hidc[64][200] | Bl[192][40]  = 66560 B
#define APAD 200
__global__ __launch_bounds__(256, 2) void mlp_fused_kernel(
    const ushort_t* __restrict__ x1b, const ushort_t* __restrict__ w1p,
    const ushort_t* __restrict__ w2p, const float* __restrict__ b1f,
    const float* __restrict__ b2f, float* __restrict__ outf) {
  extern __shared__ ushort_t smem[];
  ushort_t* A_x1 = smem;             // 64*200
  ushort_t* hidc = smem + 12800;     // 64*200
  ushort_t* Bl   = smem + 25600;     // 192*40
  int t = threadIdx.x;
  int m0 = blockIdx.x * 64;
  int lane = t & 63, wid = t >> 6;
  int wm = wid >> 1, wn = wid & 1;
  int lr = lane & 15, lg = lane >> 4;

  // stage x1 tile once, slot-permuted: 64 rows x 24 chunks of 8
  for (int s = 0; s < 6; ++s) {
    int task = t + (s << 8);
    int row = task / 24, j = task - row * 24;
    int c8 = j * 8;
    const ushort_t* p = x1b + (size_t)(m0 + row) * 192 + c8;
    ushort4 v0 = *(const ushort4*)p, v1 = *(const ushort4*)(p + 4);
    int blk = c8 & ~31, jj = (c8 & 31) >> 3;
    int b4 = ((jj & 1) << 4) | ((jj >> 1) << 2);
    *(ushort4*)&A_x1[row * APAD + blk + b4]     = v0;
    *(ushort4*)&A_x1[row * APAD + blk + b4 + 8] = v1;
  }

  int bn = t >> 2, cB = t & 3;
  int colB = ((cB & 1) << 4) | ((cB >> 1) << 2);

  f32x4 acc2[2][6];
#pragma unroll
  for (int a = 0; a < 2; ++a)
#pragma unroll
    for (int b = 0; b < 6; ++b) acc2[a][b] = (f32x4){0.f, 0.f, 0.f, 0.f};

  __syncthreads();

  for (int c = 0; c < 4; ++c) {
    // ---- fc1 for hidden chunk c ----
    const ushort_t* Wc = w1p + (size_t)(c * 192) * 192;
    const ushort_t* Br0p = Wc + (size_t)bn * 192 + (cB << 3);
    const ushort_t* Br1p = Wc + (size_t)(64 + bn) * 192 + (cB << 3);
    const ushort_t* Br2p = Wc + (size_t)(128 + bn) * 192 + (cB << 3);
    ushort4 bq0[2], bq1[2], bq2[2];
    auto LOADB = [&](int kt) {
      bq0[0] = *(const ushort4*)(Br0p + kt); bq0[1] = *(const ushort4*)(Br0p + kt + 4);
      bq1[0] = *(const ushort4*)(Br1p + kt); bq1[1] = *(const ushort4*)(Br1p + kt + 4);
      bq2[0] = *(const ushort4*)(Br2p + kt); bq2[1] = *(const ushort4*)(Br2p + kt + 4);
    };
    f32x4 acc1[2][6];
#pragma unroll
    for (int a = 0; a < 2; ++a)
#pragma unroll
      for (int b = 0; b < 6; ++b) acc1[a][b] = (f32x4){0.f, 0.f, 0.f, 0.f};

    LOADB(0);
    for (int it = 0; it < 6; ++it) {
      ushort_t* Br0 = &Bl[bn * 40];
      *(ushort4*)(Br0 + colB + 0) = bq0[0];
      *(ushort4*)(Br0 + colB + 8) = bq0[1];
      ushort_t* Br1 = &Bl[(64 + bn) * 40];
      *(ushort4*)(Br1 + colB + 0) = bq1[0];
      *(ushort4*)(Br1 + colB + 8) = bq1[1];
      ushort_t* Br2 = &Bl[(128 + bn) * 40];
      *(ushort4*)(Br2 + colB + 0) = bq2[0];
      *(ushort4*)(Br2 + colB + 8) = bq2[1];
      __syncthreads();
      if (it + 1 < 6) LOADB((it + 1) * 32);
      short8 af[2], bfv[6];
#pragma unroll
      for (int fm = 0; fm < 2; ++fm)
        af[fm] = *(const short8*)&A_x1[(wm * 32 + fm * 16 + lr) * APAD + it * 32 + lg * 8];
#pragma unroll
      for (int fn = 0; fn < 6; ++fn)
        bfv[fn] = *(const short8*)&Bl[(wn * 96 + fn * 16 + lr) * 40 + lg * 8];
#pragma unroll
      for (int fm = 0; fm < 2; ++fm)
#pragma unroll
        for (int fn = 0; fn < 6; ++fn)
          acc1[fm][fn] = __builtin_amdgcn_mfma_f32_16x16x32_bf16(af[fm], bfv[fn], acc1[fm][fn], 0, 0, 0);
      __syncthreads();
    }

    // silu + write hidden chunk to LDS (slot-permuted within 32-blocks)
#pragma unroll
    for (int fm = 0; fm < 2; ++fm) {
#pragma unroll
      for (int fn = 0; fn < 6; ++fn) {
        int col = wn * 96 + fn * 16 + lr;
        float bias = b1f[c * 192 + col];
        int blk = (col >> 5) << 5, k5 = col & 31;
        int slot = 8 * ((k5 & 15) >> 2) + ((k5 >> 4) << 2) + (k5 & 3);
#pragma unroll
        for (int r = 0; r < 4; ++r) {
          int row = wm * 32 + fm * 16 + lg * 4 + r;
          float v = acc1[fm][fn][r] + bias;
          v = v / (1.f + __expf(-v));
          hidc[row * APAD + blk + slot] = f2bf(v);
        }
      }
    }
    __syncthreads();

    // ---- fc2 partial over this chunk's K-range ----
    const ushort_t* W2c = w2p + (size_t)(c * 192);
#pragma unroll
    for (int i = 0; i < 6; ++i) {
      short8 af2[2], bf2[6];
#pragma unroll
      for (int fm = 0; fm < 2; ++fm)
        af2[fm] = *(const short8*)&hidc[(wm * 32 + fm * 16 + lr) * APAD + i * 32 + lg * 8];
#pragma unroll
      for (int fn = 0; fn < 6; ++fn) {
        int col = wn * 96 + fn * 16 + lr;
        bf2[fn] = *(const short8*)(W2c + (size_t)col * 768 + i * 32 + lg * 8);
      }
#pragma unroll
      for (int fm = 0; fm < 2; ++fm)
#pragma unroll
        for (int fn = 0; fn < 6; ++fn)
          acc2[fm][fn] = __builtin_amdgcn_mfma_f32_16x16x32_bf16(af2[fm], bf2[fn], acc2[fm][fn], 0, 0, 0);
    }
    __syncthreads();   // hidc reads done before next chunk overwrites
  }

  // epilogue: pre-LN fp32 -> out
#pragma unroll
  for (int fm = 0; fm < 2; ++fm) {
#pragma unroll
    for (int fn = 0; fn < 6; ++fn) {
      int col = wn * 96 + fn * 16 + lr;
      float bias = b2f[col];
#pragma unroll
      for (int r = 0; r < 4; ++r) {
        int row = m0 + wm * 32 + fm * 16 + lg * 4 + r;
        outf[(size_t)row * 192 + col] = acc2[fm][fn][r] + bias;
      }
    }
  }
}

// ---------------------------------------------------------------------------
// Streaming LayerNorm + residual. One wave per row, 4 waves/block.
template<int MODE>
__global__ __launch_bounds__(256) void ln_resid_kernel(
    const ushort_t* __restrict__ pre, const float* __restrict__ residf,
    const ushort_t* __restrict__ residb, const float* __restrict__ gamma,
    const float* __restrict__ beta, ushort_t* __restrict__ outb,
    float* outio) {
  int m = (blockIdx.x * 256 + threadIdx.x) >> 6;   // row
  int lane = threadIdx.x & 63;
  float v0, v1, v2;
  if (MODE == 0) {
    const ushort_t* p = pre + (size_t)m * 192;
    v0 = bf2f(p[lane]); v1 = bf2f(p[lane + 64]); v2 = bf2f(p[lane + 128]);
  } else {
    const float* p = outio + (size_t)m * 192;
    v0 = p[lane]; v1 = p[lane + 64]; v2 = p[lane + 128];
  }
  float s1 = v0 + v1 + v2;
  float s2 = v0 * v0 + v1 * v1 + v2 * v2;
#pragma unroll
  for (int o = 1; o < 64; o <<= 1) {
    s1 += __shfl_xor(s1, o);
    s2 += __shfl_xor(s2, o);
  }
  float mean = s1 * (1.f / 192.f);
  float var  = s2 * (1.f / 192.f) - mean * mean;
  float rstd = rsqrtf(fmaxf(var, 0.f) + 1e-5f);
  float l0 = (v0 - mean) * rstd * gamma[lane]       + beta[lane];
  float l1 = (v1 - mean) * rstd * gamma[lane + 64]  + beta[lane + 64];
  float l2 = (v2 - mean) * rstd * gamma[lane + 128] + beta[lane + 128];
  if (MODE == 0) {
    size_t og = (size_t)img_pos(m) * 192;
    outb[og + lane]       = f2bf(residf[og + lane]       + l0);
    outb[og + lane + 64]  = f2bf(residf[og + lane + 64]  + l1);
    outb[og + lane + 128] = f2bf(residf[og + lane + 128] + l2);
  } else {
    size_t og = (size_t)m * 192;
    outio[og + lane]       = bf2f(residb[og + lane])       + l0;
    outio[og + lane + 64]  = bf2f(residb[og + lane + 64])  + l1;
    outio[og + lane + 128] = bf2f(residb[og + lane + 128]) + l2;
  }
}

// ---------------------------------------------------------------------------
// Attention (MFMA): block = (window, head), 256 threads = 4 waves. (R10 verbatim)
__global__ __launch_bounds__(256) void attn_kernel(
    const ushort_t* __restrict__ qkv, const float* __restrict__ logit_scale,
    const float* __restrict__ tab_s, ushort_t* __restrict__ attn_out) {
  __shared__ ushort_t qs[64][40];
  __shared__ ushort_t ksl[64][40];
  __shared__ ushort_t vsl[32][80];
  __shared__ ushort_t ps[64][80];
  __shared__ float tab_l[169];
  int win = blockIdx.x, head = blockIdx.y;
  int t = threadIdx.x;
  int wi = win & 63;
  int wh0 = (wi >> 3) * 7, ww0 = (wi & 7) * 7;
  size_t base = (size_t)win * 49 * 576 + head * 32;

  for (int u = t; u < 169; u += 256) tab_l[u] = tab_s[head * 169 + u];

  for (int u = t; u < 240; u += 256) {
    int arr = u / 120, v = u - arr * 120;
    int r = 49 + (v >> 3), c4 = (v & 7) << 2;
    ushort_t* p = arr ? &ksl[r][c4] : &qs[r][c4];
    *(ushort4*)p = make_ushort4(0, 0, 0, 0);
  }

  for (int u = t; u < 2048; u += 256) {
    int key = u >> 5, d = u & 31;
    ushort_t val = 0;
    if (key < 49) val = qkv[base + (size_t)key * 576 + 384 + d];
    int kk = key & 31;
    int pc = ((key >> 5) << 5) + 8 * ((kk >> 2) & 3) + 4 * (kk >> 4) + (kk & 3);
    vsl[d][pc] = val;
  }

  float scale = __expf(fminf(logit_scale[head], 4.605170186f));  // ln(100)

  if (t < 196) {
    int r = t >> 2, c = t & 3;
    const ushort_t* qp = qkv + base + (size_t)r * 576 + c * 8;
    ushort4 qa = *(const ushort4*)qp,         qb = *(const ushort4*)(qp + 4);
    ushort4 ka = *(const ushort4*)(qp + 192), kb = *(const ushort4*)(qp + 196);
    float qf[8] = {bf2f(qa.x), bf2f(qa.y), bf2f(qa.z), bf2f(qa.w),
                   bf2f(qb.x), bf2f(qb.y), bf2f(qb.z), bf2f(qb.w)};
    float kf[8] = {bf2f(ka.x), bf2f(ka.y), bf2f(ka.z), bf2f(ka.w),
                   bf2f(kb.x), bf2f(kb.y), bf2f(kb.z), bf2f(kb.w)};
    float sq = 0.f, sk = 0.f;
#pragma unroll
    for (int d = 0; d < 8; ++d) { sq += qf[d] * qf[d]; sk += kf[d] * kf[d]; }
    sq += __shfl_xor(sq, 1); sq += __shfl_xor(sq, 2);
    sk += __shfl_xor(sk, 1); sk += __shfl_xor(sk, 2);
    float rq = scale / fmaxf(sqrtf(sq), 1e-12f);
    float rk = 1.f   / fmaxf(sqrtf(sk), 1e-12f);
    int c0 = ((c & 1) << 4) | ((c >> 1) << 2);   // {0,16,4,20}
    ushort_t* qd = &qs[r][c0];
    *(ushort4*)(qd + 0) = make_ushort4(f2bf(qf[0]*rq), f2bf(qf[1]*rq), f2bf(qf[2]*rq), f2bf(qf[3]*rq));
    *(ushort4*)(qd + 8) = make_ushort4(f2bf(qf[4]*rq), f2bf(qf[5]*rq), f2bf(qf[6]*rq), f2bf(qf[7]*rq));
    ushort_t* kd = &ksl[r][c0];
    *(ushort4*)(kd + 0) = make_ushort4(f2bf(kf[0]*rk), f2bf(kf[1]*rk), f2bf(kf[2]*rk), f2bf(kf[3]*rk));
    *(ushort4*)(kd + 8) = make_ushort4(f2bf(kf[4]*rk), f2bf(kf[5]*rk), f2bf(kf[6]*rk), f2bf(kf[7]*rk));
  }
  __syncthreads();

  int lane = t & 63, w = t >> 6;
  int lr = lane & 15, lg = lane >> 4;

  short8 aq = *(const short8*)&qs[w * 16 + lr][lg * 8];
  f32x4 acc[4];
#pragma unroll
  for (int fn = 0; fn < 4; ++fn) {
    acc[fn] = (f32x4){0.f, 0.f, 0.f, 0.f};
    short8 bk = *(const short8*)&ksl[fn * 16 + lr][lg * 8];
    acc[fn] = __builtin_amdgcn_mfma_f32_16x16x32_bf16(aq, bk, acc[fn], 0, 0, 0);
  }

  float rsum[4];
#pragma unroll
  for (int r = 0; r < 4; ++r) {
    int row = w * 16 + lg * 4 + r;
    int rd = (row * 9363) >> 16, rm = row - 7 * rd;
    int gr = region3(wh0 + rd) * 3 + region3(ww0 + rm);
    bool rv = row < 49;
    float sv[4];
#pragma unroll
    for (int fn = 0; fn < 4; ++fn) {
      int col = fn * 16 + lr;
      int jd = (col * 9363) >> 16, jm = col - 7 * jd;
      int gj = region3(wh0 + jd) * 3 + region3(ww0 + jm);
      bool cv = rv && (col < 49);
      int idx = cv ? (rd - jd + 6) * 13 + (rm - jm + 6) : 0;
      float s = acc[fn][r] + tab_l[idx] + (gr == gj ? 0.f : -100.f);
      sv[fn] = cv ? s : -1e30f;
    }
    float m = fmaxf(fmaxf(sv[0], sv[1]), fmaxf(sv[2], sv[3]));
#pragma unroll
    for (int o = 1; o < 16; o <<= 1) m = fmaxf(m, __shfl_xor(m, o));
    float sum = 0.f;
#pragma unroll
    for (int fn = 0; fn < 4; ++fn) {
      float e = __expf(sv[fn] - m);
      sum += e;
      int pc = ((fn >> 1) << 5) + 8 * (lr >> 2) + ((fn & 1) << 2) + (lr & 3);
      ps[row][pc] = f2bf(e);
    }
#pragma unroll
    for (int o = 1; o < 16; o <<= 1) sum += __shfl_xor(sum, o);
    rsum[r] = 1.f / sum;
  }
  __syncthreads();

  short8 ap0 = *(const short8*)&ps[w * 16 + lr][lg * 8];
  short8 ap1 = *(const short8*)&ps[w * 16 + lr][32 + lg * 8];
  f32x4 o2[2];
#pragma unroll
  for (int f = 0; f < 2; ++f) {
    o2[f] = (f32x4){0.f, 0.f, 0.f, 0.f};
    short8 bv0 = *(const short8*)&vsl[f * 16 + lr][lg * 8];
    short8 bv1 = *(const short8*)&vsl[f * 16 + lr][32 + lg * 8];
    o2[f] = __builtin_amdgcn_mfma_f32_16x16x32_bf16(ap0, bv0, o2[f], 0, 0, 0);
    o2[f] = __builtin_amdgcn_mfma_f32_16x16x32_bf16(ap1, bv1, o2[f], 0, 0, 0);
  }
#pragma unroll
  for (int f = 0; f < 2; ++f) {
#pragma unroll
    for (int r = 0; r < 4; ++r) {
      int row = w * 16 + lg * 4 + r;
      if (row < 49)
        attn_out[((size_t)win * 49 + row) * 192 + head * 32 + f * 16 + lr] =
            f2bf(o2[f][r] * rsum[r]);
    }
  }
}

// ---------------------------------------------------------------------------
extern "C" void kernel_launch(void* const* d_in, const int* in_sizes, int n_in,
                              void* d_out, int out_size, void* d_ws, size_t ws_size,
                              hipStream_t stream) {
  (void)in_sizes; (void)n_in; (void)out_size; (void)ws_size;
  const float* x    = (const float*)d_in[0];
  const float* qkvw = (const float*)d_in[1];
  const float* qb   = (const float*)d_in[2];
  const float* vb   = (const float*)d_in[3];
  const float* ls   = (const float*)d_in[4];
  const float* cw1  = (const float*)d_in[5];
  const float* cb1  = (const float*)d_in[6];
  const float* cw2  = (const float*)d_in[7];
  const float* pw   = (const float*)d_in[8];
  const float* pb   = (const float*)d_in[9];
  const float* n1g  = (const float*)d_in[10];
  const float* n1b  = (const float*)d_in[11];
  const float* n2g  = (const float*)d_in[12];
  const float* n2b  = (const float*)d_in[13];
  const float* f1w  = (const float*)d_in[14];
  const float* f1b  = (const float*)d_in[15];
  const float* f2w  = (const float*)d_in[16];
  const float* f2b  = (const float*)d_in[17];
  float* out = (float*)d_out;

  char* ws = (char*)d_ws;
  ushort_t* wq_bf = (ushort_t*)ws;                 // 110592
  ushort_t* wp_bf = wq_bf + 110592;                // 36864
  ushort_t* w1_bf = wp_bf + 36864;                 // 147456 (plain cvt)
  ushort_t* w2_bf = w1_bf + 147456;                // 147456 (k-permuted, K=768)
  float*    tab_s = (float*)(w2_bf + 147456);      // 6*169 floats
  const size_t OFF_BIG = 1 << 20;
  ushort_t* qkv_out = (ushort_t*)(ws + OFF_BIG);
  ushort_t* xw_bf   = (ushort_t*)(ws + OFF_BIG + 115605504);
  ushort_t* attn_o  = (ushort_t*)(ws + OFF_BIG + 115605504);
  ushort_t* x1_bf   = (ushort_t*)(ws + OFF_BIG + 154140672);

  cvt_kernel<<<(110592 + 255) / 256, 256, 0, stream>>>(qkvw, wq_bf, 110592);
  cvt_kernel<<<(36864  + 255) / 256, 256, 0, stream>>>(pw,   wp_bf, 36864);
  cvt_kernel<<<(147456 + 255) / 256, 256, 0, stream>>>(f1w,  w1_bf, 147456);
  cvt_perm_kernel<<<(147456 + 255) / 256, 256, 0, stream>>>(f2w, w2_bf, 147456, 768);
  cpb_kernel<<<169, 256, 0, stream>>>(cw1, cb1, cw2, tab_s);
  gather_cvt_kernel<<<9408, 256, 0, stream>>>(x, xw_bf);

  // qkv
  gemm_n192<192, 0><<<dim3(784, 3), 256, 0, stream>>>(xw_bf, wq_bf, qb, vb, qkv_out, nullptr, 576);
  // attention
  attn_kernel<<<dim3(2048, 6), 256, 0, stream>>>(qkv_out, ls, tab_s, attn_o);
  // proj (pre-LN, in-place over attn_o) + LN1/residual
  gemm_n192<192, 2><<<dim3(784, 1), 256, 0, stream>>>(attn_o, wp_bf, pb, nullptr, attn_o, nullptr, 192);
  ln_resid_kernel<0><<<25088, 256, 0, stream>>>(attn_o, x, nullptr, n1g, n1b, x1_bf, nullptr);
  // fused MLP (fc1+silu+fc2, hidden stays in LDS) -> pre-LN fp32 in d_out
  mlp_fused_kernel<<<1568, 256, 66560, stream>>>(x1_bf, w1_bf, w2_bf, f1b, f2b, out);
  // LN2/residual in-place on d_out
  ln_resid_kernel<1><<<25088, 256, 0, stream>>>(nullptr, nullptr, x1_bf, n2g, n2b, nullptr, out);
}

// Round 12
// 445.419 us; speedup vs baseline: 1.0908x; 1.0908x over previous
//
#include <hip/hip_runtime.h>

// ============================================================================
// Swin V2 block, round 12 = R10 revert (422us best) + two isolated changes:
//  (1) qkv -> barrier-free direct-fragment GEMM: xw_bf & wq_bf stored
//      k-permuted (slot(k)=8*((k%16)/4)+4*(k/16)+k%4, R8-verified) so each
//      MFMA fragment = one contiguous 16B global load. No LDS, no barriers.
//  (2) gemm_n192 template: 8B load pairs merged to 16B dwordx4.
// R11 post-mortem: mlp_fused FAILED (239 vs 160): traffic win (FETCH 26MB)
// but 78us/block - small MFMA batches, 60 barriers, serial fc1->fc2. Reverted.
// MFMA layout (HW-verified): A row=lane%16, slot=lane/16*8..+7;
// C/D col=lane%16, row=4*(lane/16)+reg.
// ============================================================================

typedef unsigned short ushort_t;
using f32x4  = __attribute__((ext_vector_type(4))) float;
using short8 = __attribute__((ext_vector_type(8))) short;
union LD16 { short8 v; ushort4 h[2]; };

__device__ __forceinline__ ushort_t f2bf(float f) {
  union { float f; unsigned u; } v; v.f = f;
  unsigned r = v.u + 0x7fffu + ((v.u >> 16) & 1u);
  return (ushort_t)(r >> 16);
}
__device__ __forceinline__ float bf2f(ushort_t u) {
  union { unsigned u; float f; } v; v.u = ((unsigned)u) << 16;
  return v.f;
}

// windowed-token index m -> image row index (same map for gather and scatter)
__device__ __forceinline__ int img_pos(int m) {
  int win = m / 49, n = m - win * 49;
  int b = win >> 6, wi = win & 63;
  int nd = n / 7, nm = n - nd * 7;
  int hs = (wi >> 3) * 7 + nd;
  int ws = (wi & 7) * 7 + nm;
  int h = hs + 3; if (h >= 56) h -= 56;
  int w = ws + 3; if (w >= 56) w -= 56;
  return b * 3136 + h * 56 + w;
}

__device__ __forceinline__ int region3(int a) { return a < 49 ? 0 : (a < 53 ? 1 : 2); }

// ---------------------------------------------------------------------------
__global__ void cvt_kernel(const float* __restrict__ in, ushort_t* __restrict__ out, int n) {
  int i = blockIdx.x * 256 + threadIdx.x;
  if (i < n) out[i] = f2bf(in[i]);
}

// weight convert + k-permute within each 32-block of the K dim
__global__ void cvt_perm_kernel(const float* __restrict__ in, ushort_t* __restrict__ out,
                                int n, int K) {
  int i = blockIdx.x * 256 + threadIdx.x;
  if (i >= n) return;
  int row = i / K, j = i - row * K;
  int k = j & 31;
  int s = (j & ~31) + (((k & 15) >> 2) << 3) + ((k >> 4) << 2) + (k & 3);
  out[row * K + s] = f2bf(in[i]);
}

// gather shifted windows + cvt + k-permute (R8-verified):
// xw[m][slot(c)] = bf16(x[img_pos(m)][c])
__global__ __launch_bounds__(256) void gather_cvt_kernel(
    const float* __restrict__ x, ushort_t* __restrict__ xw) {
  int i8 = blockIdx.x * 256 + threadIdx.x;      // 100352*24 tasks of 8 elems
  int m = i8 / 24, c8 = (i8 - m * 24) * 8;
  const float* p = x + (size_t)img_pos(m) * 192 + c8;
  float4 a = *(const float4*)p, b = *(const float4*)(p + 4);
  ushort_t* q = xw + (size_t)m * 192;
  int blk = c8 & ~31;
  int jj = (c8 & 31) >> 3;
  int b4 = ((jj & 1) << 4) | ((jj >> 1) << 2);
  *(ushort4*)(q + blk + b4)     = make_ushort4(f2bf(a.x), f2bf(a.y), f2bf(a.z), f2bf(a.w));
  *(ushort4*)(q + blk + b4 + 8) = make_ushort4(f2bf(b.x), f2bf(b.y), f2bf(b.z), f2bf(b.w));
}

// ---------------------------------------------------------------------------
// CPB: tab_s[head][e] = 16*sigmoid( relu(REL_TABLE[e] @ w1.T + b1) @ w2.T )
__global__ __launch_bounds__(256) void cpb_kernel(
    const float* __restrict__ w1, const float* __restrict__ b1,
    const float* __restrict__ w2, float* __restrict__ tab_s) {
  int e = blockIdx.x;            // 0..168
  int t = threadIdx.x;           // 0..255
  int i = e / 13, j = e - 13 * (e / 13);
  auto cval = [](int a) -> float {
    float r = (a - 6) * (8.0f / 6.0f);
    float v = log2f(fabsf(r) + 1.f) * (1.f / 3.f);
    return r < 0.f ? -v : v;
  };
  float ci = cval(i), cj = cval(j);
  float h = fmaxf(ci * w1[2 * t] + cj * w1[2 * t + 1] + b1[t], 0.f);
  __shared__ float red[256];
  for (int head = 0; head < 6; ++head) {
    red[t] = h * w2[head * 256 + t];
    __syncthreads();
    for (int st = 128; st > 0; st >>= 1) {
      if (t < st) red[t] += red[t + st];
      __syncthreads();
    }
    if (t == 0) tab_s[head * 169 + e] = 16.f / (1.f + __expf(-red[0]));
    __syncthreads();
  }
}

// ---------------------------------------------------------------------------
// qkv: barrier-free direct-fragment GEMM. A (xw, k-permuted), B (wq,
// k-permuted). Fragment (fm/fn, kt) = one 16B load at row*192 + kt + lg*8.
// No LDS. Output standard cols (bias = concat(q_bias,0,v_bias)).
__global__ __launch_bounds__(256) void gemm_direct_qkv(
    const ushort_t* __restrict__ Ap, const ushort_t* __restrict__ Wp,
    const float* __restrict__ b0, const float* __restrict__ b1,
    ushort_t* __restrict__ out, int NTOT) {
  int t = threadIdx.x;
  int m0 = blockIdx.x * 128, n0 = blockIdx.y * 192;
  int lane = t & 63, wid = t >> 6;
  int wm = wid >> 1, wn = wid & 1;
  int lr = lane & 15, lg = lane >> 4;

  const ushort_t* ar[4];
  const ushort_t* br[6];
#pragma unroll
  for (int fm = 0; fm < 4; ++fm)
    ar[fm] = Ap + (size_t)(m0 + wm * 64 + fm * 16 + lr) * 192 + lg * 8;
#pragma unroll
  for (int fn = 0; fn < 6; ++fn)
    br[fn] = Wp + (size_t)(n0 + wn * 96 + fn * 16 + lr) * 192 + lg * 8;

  f32x4 acc[4][6];
#pragma unroll
  for (int a = 0; a < 4; ++a)
#pragma unroll
    for (int b = 0; b < 6; ++b) acc[a][b] = (f32x4){0.f, 0.f, 0.f, 0.f};

#pragma unroll
  for (int kt = 0; kt < 192; kt += 32) {
    short8 af[4], bfv[6];
#pragma unroll
    for (int fm = 0; fm < 4; ++fm) af[fm] = *(const short8*)(ar[fm] + kt);
#pragma unroll
    for (int fn = 0; fn < 6; ++fn) bfv[fn] = *(const short8*)(br[fn] + kt);
#pragma unroll
    for (int fm = 0; fm < 4; ++fm)
#pragma unroll
      for (int fn = 0; fn < 6; ++fn)
        acc[fm][fn] = __builtin_amdgcn_mfma_f32_16x16x32_bf16(af[fm], bfv[fn], acc[fm][fn], 0, 0, 0);
  }
#pragma unroll
  for (int fm = 0; fm < 4; ++fm) {
#pragma unroll
    for (int fn = 0; fn < 6; ++fn) {
      int col = n0 + wn * 96 + fn * 16 + lr;
      float bias = (col < 192) ? b0[col] : ((col < 384) ? 0.f : b1[col - 384]);
#pragma unroll
      for (int r = 0; r < 4; ++r) {
        int row = m0 + wm * 64 + fm * 16 + lg * 4 + r;
        out[(size_t)row * NTOT + col] = f2bf(acc[fm][fn][r] + bias);
      }
    }
  }
}

// ---------------------------------------------------------------------------
// GEMM, tile 128(M) x 192(N), K-step 32, 4 waves, bf16 A, T14 reg prefetch,
// 16B global loads. MODE 1: fc1(silu)  MODE 2: proj  MODE 3: fp32 out (fc2)
template<int KTOT, int MODE>
__global__ __launch_bounds__(256) void gemm_n192(
    const ushort_t* __restrict__ Ab, const ushort_t* __restrict__ W,
    const float* __restrict__ b0, ushort_t* out, float* outf, int NTOT) {
  __shared__ ushort_t Al[128][40];
  __shared__ ushort_t Bl[192][40];
  int t = threadIdx.x;
  int m0 = blockIdx.x * 128, n0 = blockIdx.y * 192;

  int arow = t >> 1, akoff = (t & 1) << 4;
  const ushort_t* Arowp = Ab + (size_t)(m0 + arow) * KTOT + akoff;
  int colA = akoff ? 4 : 0;

  int lane = t & 63, wid = t >> 6;
  int wm = wid >> 1, wn = wid & 1;
  int lr = lane & 15, lg = lane >> 4;

  int bn = t >> 2, cB = t & 3;
  const ushort_t* Browp  = W + (size_t)(n0 + bn) * KTOT + (cB << 3);
  const ushort_t* Browp2 = W + (size_t)(n0 + 64 + bn) * KTOT + (cB << 3);
  const ushort_t* Browp3 = W + (size_t)(n0 + 128 + bn) * KTOT + (cB << 3);
  int colB = ((cB & 1) << 4) | ((cB >> 1) << 2);   // {0,16,4,20}

  f32x4 acc[4][6];
#pragma unroll
  for (int a = 0; a < 4; ++a)
#pragma unroll
    for (int b = 0; b < 6; ++b) acc[a][b] = (f32x4){0.f, 0.f, 0.f, 0.f};

  LD16 A01, A23, B0, B1, B2;
  auto LOADREGS = [&](int kt) {
    A01.v = *(const short8*)(Arowp + kt);
    A23.v = *(const short8*)(Arowp + kt + 8);
    B0.v  = *(const short8*)(Browp + kt);
    B1.v  = *(const short8*)(Browp2 + kt);
    B2.v  = *(const short8*)(Browp3 + kt);
  };

  const int NT = KTOT / 32;
  LOADREGS(0);
  for (int it = 0; it < NT; ++it) {
    ushort_t* Ar = &Al[arow][0];
    *(ushort4*)(Ar + colA +  0) = A01.h[0];
    *(ushort4*)(Ar + colA +  8) = A01.h[1];
    *(ushort4*)(Ar + colA + 16) = A23.h[0];
    *(ushort4*)(Ar + colA + 24) = A23.h[1];
    ushort_t* Br0 = &Bl[bn][0];
    *(ushort4*)(Br0 + colB + 0) = B0.h[0];
    *(ushort4*)(Br0 + colB + 8) = B0.h[1];
    ushort_t* Br1 = &Bl[64 + bn][0];
    *(ushort4*)(Br1 + colB + 0) = B1.h[0];
    *(ushort4*)(Br1 + colB + 8) = B1.h[1];
    ushort_t* Br2 = &Bl[128 + bn][0];
    *(ushort4*)(Br2 + colB + 0) = B2.h[0];
    *(ushort4*)(Br2 + colB + 8) = B2.h[1];
    __syncthreads();
    if (it + 1 < NT) LOADREGS((it + 1) * 32);   // in flight during MFMAs
    short8 af[4], bfv[6];
#pragma unroll
    for (int fm = 0; fm < 4; ++fm)
      af[fm] = *(const short8*)&Al[wm * 64 + fm * 16 + lr][lg * 8];
#pragma unroll
    for (int fn = 0; fn < 6; ++fn)
      bfv[fn] = *(const short8*)&Bl[wn * 96 + fn * 16 + lr][lg * 8];
#pragma unroll
    for (int fm = 0; fm < 4; ++fm)
#pragma unroll
      for (int fn = 0; fn < 6; ++fn)
        acc[fm][fn] = __builtin_amdgcn_mfma_f32_16x16x32_bf16(af[fm], bfv[fn], acc[fm][fn], 0, 0, 0);
    if (it + 1 < NT) __syncthreads();
  }
#pragma unroll
  for (int fm = 0; fm < 4; ++fm) {
#pragma unroll
    for (int fn = 0; fn < 6; ++fn) {
      int col = n0 + wn * 96 + fn * 16 + lr;
      float bias = b0[col];
#pragma unroll
      for (int r = 0; r < 4; ++r) {
        int row = m0 + wm * 64 + fm * 16 + lg * 4 + r;
        float v = acc[fm][fn][r] + bias;
        if (MODE == 1) v = v / (1.f + __expf(-v));   // silu
        if (MODE == 3) outf[(size_t)row * NTOT + col] = v;
        else           out[(size_t)row * NTOT + col] = f2bf(v);
      }
    }
  }
}

// ---------------------------------------------------------------------------
// Streaming LayerNorm + residual. One wave per row, 4 waves/block.
template<int MODE>
__global__ __launch_bounds__(256) void ln_resid_kernel(
    const ushort_t* __restrict__ pre, const float* __restrict__ residf,
    const ushort_t* __restrict__ residb, const float* __restrict__ gamma,
    const float* __restrict__ beta, ushort_t* __restrict__ outb,
    float* outio) {
  int m = (blockIdx.x * 256 + threadIdx.x) >> 6;   // row
  int lane = threadIdx.x & 63;
  float v0, v1, v2;
  if (MODE == 0) {
    const ushort_t* p = pre + (size_t)m * 192;
    v0 = bf2f(p[lane]); v1 = bf2f(p[lane + 64]); v2 = bf2f(p[lane + 128]);
  } else {
    const float* p = outio + (size_t)m * 192;
    v0 = p[lane]; v1 = p[lane + 64]; v2 = p[lane + 128];
  }
  float s1 = v0 + v1 + v2;
  float s2 = v0 * v0 + v1 * v1 + v2 * v2;
#pragma unroll
  for (int o = 1; o < 64; o <<= 1) {
    s1 += __shfl_xor(s1, o);
    s2 += __shfl_xor(s2, o);
  }
  float mean = s1 * (1.f / 192.f);
  float var  = s2 * (1.f / 192.f) - mean * mean;
  float rstd = rsqrtf(fmaxf(var, 0.f) + 1e-5f);
  float l0 = (v0 - mean) * rstd * gamma[lane]       + beta[lane];
  float l1 = (v1 - mean) * rstd * gamma[lane + 64]  + beta[lane + 64];
  float l2 = (v2 - mean) * rstd * gamma[lane + 128] + beta[lane + 128];
  if (MODE == 0) {
    size_t og = (size_t)img_pos(m) * 192;
    outb[og + lane]       = f2bf(residf[og + lane]       + l0);
    outb[og + lane + 64]  = f2bf(residf[og + lane + 64]  + l1);
    outb[og + lane + 128] = f2bf(residf[og + lane + 128] + l2);
  } else {
    size_t og = (size_t)m * 192;
    outio[og + lane]       = bf2f(residb[og + lane])       + l0;
    outio[og + lane + 64]  = bf2f(residb[og + lane + 64])  + l1;
    outio[og + lane + 128] = bf2f(residb[og + lane + 128]) + l2;
  }
}

// ---------------------------------------------------------------------------
// Attention (MFMA): block = (window, head), 256 threads = 4 waves. (R10 verbatim)
__global__ __launch_bounds__(256) void attn_kernel(
    const ushort_t* __restrict__ qkv, const float* __restrict__ logit_scale,
    const float* __restrict__ tab_s, ushort_t* __restrict__ attn_out) {
  __shared__ ushort_t qs[64][40];
  __shared__ ushort_t ksl[64][40];
  __shared__ ushort_t vsl[32][80];
  __shared__ ushort_t ps[64][80];
  __shared__ float tab_l[169];
  int win = blockIdx.x, head = blockIdx.y;
  int t = threadIdx.x;
  int wi = win & 63;
  int wh0 = (wi >> 3) * 7, ww0 = (wi & 7) * 7;
  size_t base = (size_t)win * 49 * 576 + head * 32;

  for (int u = t; u < 169; u += 256) tab_l[u] = tab_s[head * 169 + u];

  for (int u = t; u < 240; u += 256) {
    int arr = u / 120, v = u - arr * 120;
    int r = 49 + (v >> 3), c4 = (v & 7) << 2;
    ushort_t* p = arr ? &ksl[r][c4] : &qs[r][c4];
    *(ushort4*)p = make_ushort4(0, 0, 0, 0);
  }

  for (int u = t; u < 2048; u += 256) {
    int key = u >> 5, d = u & 31;
    ushort_t val = 0;
    if (key < 49) val = qkv[base + (size_t)key * 576 + 384 + d];
    int kk = key & 31;
    int pc = ((key >> 5) << 5) + 8 * ((kk >> 2) & 3) + 4 * (kk >> 4) + (kk & 3);
    vsl[d][pc] = val;
  }

  float scale = __expf(fminf(logit_scale[head], 4.605170186f));  // ln(100)

  if (t < 196) {
    int r = t >> 2, c = t & 3;
    const ushort_t* qp = qkv + base + (size_t)r * 576 + c * 8;
    ushort4 qa = *(const ushort4*)qp,         qb = *(const ushort4*)(qp + 4);
    ushort4 ka = *(const ushort4*)(qp + 192), kb = *(const ushort4*)(qp + 196);
    float qf[8] = {bf2f(qa.x), bf2f(qa.y), bf2f(qa.z), bf2f(qa.w),
                   bf2f(qb.x), bf2f(qb.y), bf2f(qb.z), bf2f(qb.w)};
    float kf[8] = {bf2f(ka.x), bf2f(ka.y), bf2f(ka.z), bf2f(ka.w),
                   bf2f(kb.x), bf2f(kb.y), bf2f(kb.z), bf2f(kb.w)};
    float sq = 0.f, sk = 0.f;
#pragma unroll
    for (int d = 0; d < 8; ++d) { sq += qf[d] * qf[d]; sk += kf[d] * kf[d]; }
    sq += __shfl_xor(sq, 1); sq += __shfl_xor(sq, 2);
    sk += __shfl_xor(sk, 1); sk += __shfl_xor(sk, 2);
    float rq = scale / fmaxf(sqrtf(sq), 1e-12f);
    float rk = 1.f   / fmaxf(sqrtf(sk), 1e-12f);
    int c0 = ((c & 1) << 4) | ((c >> 1) << 2);   // {0,16,4,20}
    ushort_t* qd = &qs[r][c0];
    *(ushort4*)(qd + 0) = make_ushort4(f2bf(qf[0]*rq), f2bf(qf[1]*rq), f2bf(qf[2]*rq), f2bf(qf[3]*rq));
    *(ushort4*)(qd + 8) = make_ushort4(f2bf(qf[4]*rq), f2bf(qf[5]*rq), f2bf(qf[6]*rq), f2bf(qf[7]*rq));
    ushort_t* kd = &ksl[r][c0];
    *(ushort4*)(kd + 0) = make_ushort4(f2bf(kf[0]*rk), f2bf(kf[1]*rk), f2bf(kf[2]*rk), f2bf(kf[3]*rk));
    *(ushort4*)(kd + 8) = make_ushort4(f2bf(kf[4]*rk), f2bf(kf[5]*rk), f2bf(kf[6]*rk), f2bf(kf[7]*rk));
  }
  __syncthreads();

  int lane = t & 63, w = t >> 6;
  int lr = lane & 15, lg = lane >> 4;

  short8 aq = *(const short8*)&qs[w * 16 + lr][lg * 8];
  f32x4 acc[4];
#pragma unroll
  for (int fn = 0; fn < 4; ++fn) {
    acc[fn] = (f32x4){0.f, 0.f, 0.f, 0.f};
    short8 bk = *(const short8*)&ksl[fn * 16 + lr][lg * 8];
    acc[fn] = __builtin_amdgcn_mfma_f32_16x16x32_bf16(aq, bk, acc[fn], 0, 0, 0);
  }

  float rsum[4];
#pragma unroll
  for (int r = 0; r < 4; ++r) {
    int row = w * 16 + lg * 4 + r;
    int rd = (row * 9363) >> 16, rm = row - 7 * rd;
    int gr = region3(wh0 + rd) * 3 + region3(ww0 + rm);
    bool rv = row < 49;
    float sv[4];
#pragma unroll
    for (int fn = 0; fn < 4; ++fn) {
      int col = fn * 16 + lr;
      int jd = (col * 9363) >> 16, jm = col - 7 * jd;
      int gj = region3(wh0 + jd) * 3 + region3(ww0 + jm);
      bool cv = rv && (col < 49);
      int idx = cv ? (rd - jd + 6) * 13 + (rm - jm + 6) : 0;
      float s = acc[fn][r] + tab_l[idx] + (gr == gj ? 0.f : -100.f);
      sv[fn] = cv ? s : -1e30f;
    }
    float m = fmaxf(fmaxf(sv[0], sv[1]), fmaxf(sv[2], sv[3]));
#pragma unroll
    for (int o = 1; o < 16; o <<= 1) m = fmaxf(m, __shfl_xor(m, o));
    float sum = 0.f;
#pragma unroll
    for (int fn = 0; fn < 4; ++fn) {
      float e = __expf(sv[fn] - m);
      sum += e;
      int pc = ((fn >> 1) << 5) + 8 * (lr >> 2) + ((fn & 1) << 2) + (lr & 3);
      ps[row][pc] = f2bf(e);
    }
#pragma unroll
    for (int o = 1; o < 16; o <<= 1) sum += __shfl_xor(sum, o);
    rsum[r] = 1.f / sum;
  }
  __syncthreads();

  short8 ap0 = *(const short8*)&ps[w * 16 + lr][lg * 8];
  short8 ap1 = *(const short8*)&ps[w * 16 + lr][32 + lg * 8];
  f32x4 o2[2];
#pragma unroll
  for (int f = 0; f < 2; ++f) {
    o2[f] = (f32x4){0.f, 0.f, 0.f, 0.f};
    short8 bv0 = *(const short8*)&vsl[f * 16 + lr][lg * 8];
    short8 bv1 = *(const short8*)&vsl[f * 16 + lr][32 + lg * 8];
    o2[f] = __builtin_amdgcn_mfma_f32_16x16x32_bf16(ap0, bv0, o2[f], 0, 0, 0);
    o2[f] = __builtin_amdgcn_mfma_f32_16x16x32_bf16(ap1, bv1, o2[f], 0, 0, 0);
  }
#pragma unroll
  for (int f = 0; f < 2; ++f) {
#pragma unroll
    for (int r = 0; r < 4; ++r) {
      int row = w * 16 + lg * 4 + r;
      if (row < 49)
        attn_out[((size_t)win * 49 + row) * 192 + head * 32 + f * 16 + lr] =
            f2bf(o2[f][r] * rsum[r]);
    }
  }
}

// ---------------------------------------------------------------------------
extern "C" void kernel_launch(void* const* d_in, const int* in_sizes, int n_in,
                              void* d_out, int out_size, void* d_ws, size_t ws_size,
                              hipStream_t stream) {
  (void)in_sizes; (void)n_in; (void)out_size; (void)ws_size;
  const float* x    = (const float*)d_in[0];
  const float* qkvw = (const float*)d_in[1];
  const float* qb   = (const float*)d_in[2];
  const float* vb   = (const float*)d_in[3];
  const float* ls   = (const float*)d_in[4];
  const float* cw1  = (const float*)d_in[5];
  const float* cb1  = (const float*)d_in[6];
  const float* cw2  = (const float*)d_in[7];
  const float* pw   = (const float*)d_in[8];
  const float* pb   = (const float*)d_in[9];
  const float* n1g  = (const float*)d_in[10];
  const float* n1b  = (const float*)d_in[11];
  const float* n2g  = (const float*)d_in[12];
  const float* n2b  = (const float*)d_in[13];
  const float* f1w  = (const float*)d_in[14];
  const float* f1b  = (const float*)d_in[15];
  const float* f2w  = (const float*)d_in[16];
  const float* f2b  = (const float*)d_in[17];
  float* out = (float*)d_out;

  char* ws = (char*)d_ws;
  ushort_t* wq_bf = (ushort_t*)ws;                 // 110592 (k-permuted)
  ushort_t* wp_bf = wq_bf + 110592;                // 36864
  ushort_t* w1_bf = wp_bf + 36864;                 // 147456
  ushort_t* w2_bf = w1_bf + 147456;                // 147456
  float*    tab_s = (float*)(w2_bf + 147456);      // 6*169 floats
  const size_t OFF_BIG = 1 << 20;
  ushort_t* qkv_out = (ushort_t*)(ws + OFF_BIG);
  ushort_t* xw_bf   = (ushort_t*)(ws + OFF_BIG + 115605504);
  ushort_t* attn_o  = (ushort_t*)(ws + OFF_BIG + 115605504);
  ushort_t* x1_bf   = (ushort_t*)(ws + OFF_BIG + 154140672);
  ushort_t* hmid    = (ushort_t*)(ws + OFF_BIG);   // 100352*768 bf16 over R1+R2

  cvt_perm_kernel<<<(110592 + 255) / 256, 256, 0, stream>>>(qkvw, wq_bf, 110592, 192);
  cvt_kernel<<<(36864  + 255) / 256, 256, 0, stream>>>(pw,   wp_bf, 36864);
  cvt_kernel<<<(147456 + 255) / 256, 256, 0, stream>>>(f1w,  w1_bf, 147456);
  cvt_kernel<<<(147456 + 255) / 256, 256, 0, stream>>>(f2w,  w2_bf, 147456);
  cpb_kernel<<<169, 256, 0, stream>>>(cw1, cb1, cw2, tab_s);
  gather_cvt_kernel<<<9408, 256, 0, stream>>>(x, xw_bf);

  // qkv: direct-fragment, no LDS/barriers
  gemm_direct_qkv<<<dim3(784, 3), 256, 0, stream>>>(xw_bf, wq_bf, qb, vb, qkv_out, 576);
  // attention
  attn_kernel<<<dim3(2048, 6), 256, 0, stream>>>(qkv_out, ls, tab_s, attn_o);
  // proj (pre-LN, in-place over attn_o) + LN1/residual
  gemm_n192<192, 2><<<dim3(784, 1), 256, 0, stream>>>(attn_o, wp_bf, pb, attn_o, nullptr, 192);
  ln_resid_kernel<0><<<25088, 256, 0, stream>>>(attn_o, x, nullptr, n1g, n1b, x1_bf, nullptr);
  // fc1 (silu)
  gemm_n192<192, 1><<<dim3(784, 4), 256, 0, stream>>>(x1_bf, w1_bf, f1b, hmid, nullptr, 768);
  // fc2 (pre-LN fp32 -> d_out) + LN2/residual in-place
  gemm_n192<768, 3><<<dim3(784, 1), 256, 0, stream>>>(hmid, w2_bf, f2b, nullptr, out, 192);
  ln_resid_kernel<1><<<25088, 256, 0, stream>>>(nullptr, nullptr, x1_bf, n2g, n2b, nullptr, out);
}

// Round 13
// 402.735 us; speedup vs baseline: 1.2064x; 1.1060x over previous
//
#include <hip/hip_runtime.h>

// ============================================================================
// Swin V2 block, round 13 = R10 base (422us best; R11 fusion and R12
// direct-frag both reverted) + 512-thread GEMM blocks.
// Occupancy theory: acc[4][6]=96 AGPR + 124 arch = 220 unified -> 8 waves/CU
// (25% cap, measured 19-20%). 8 waves/block with 32x96 wave-tiles ->
// acc[2][6]=48, ~128 unified (pinned by __launch_bounds__(512,4)) ->
// 16 waves/CU (50%), 2x TLP, same tile/barriers/MFMA-per-block.
// Staging (+T14 reg prefetch) on threads<256 only; all 8 waves compute.
// MFMA layout (HW-verified): A row=lane%16, k=4*(lane/16)+{0..3}(+16);
// C/D col=lane%16, row=4*(lane/16)+reg. LDS perm col=8*((k%16)/4)+4*(k/16)+k%4.
// ============================================================================

typedef unsigned short ushort_t;
using f32x4  = __attribute__((ext_vector_type(4))) float;
using short8 = __attribute__((ext_vector_type(8))) short;
union LD16 { short8 v; ushort4 h[2]; };

__device__ __forceinline__ ushort_t f2bf(float f) {
  union { float f; unsigned u; } v; v.f = f;
  unsigned r = v.u + 0x7fffu + ((v.u >> 16) & 1u);
  return (ushort_t)(r >> 16);
}
__device__ __forceinline__ float bf2f(ushort_t u) {
  union { unsigned u; float f; } v; v.u = ((unsigned)u) << 16;
  return v.f;
}

// windowed-token index m -> image row index (same map for gather and scatter)
__device__ __forceinline__ int img_pos(int m) {
  int win = m / 49, n = m - win * 49;
  int b = win >> 6, wi = win & 63;
  int nd = n / 7, nm = n - nd * 7;
  int hs = (wi >> 3) * 7 + nd;
  int ws = (wi & 7) * 7 + nm;
  int h = hs + 3; if (h >= 56) h -= 56;
  int w = ws + 3; if (w >= 56) w -= 56;
  return b * 3136 + h * 56 + w;
}

__device__ __forceinline__ int region3(int a) { return a < 49 ? 0 : (a < 53 ? 1 : 2); }

// ---------------------------------------------------------------------------
__global__ void cvt_kernel(const float* __restrict__ in, ushort_t* __restrict__ out, int n) {
  int i = blockIdx.x * 256 + threadIdx.x;
  if (i < n) out[i] = f2bf(in[i]);
}

// gather shifted-window rows + convert to bf16: xw[m][c] = bf16(x[img_pos(m)][c])
__global__ __launch_bounds__(256) void gather_cvt_kernel(
    const float* __restrict__ x, ushort_t* __restrict__ xw) {
  int i8 = blockIdx.x * 256 + threadIdx.x;      // 100352*24 tasks of 8 elems
  int m = i8 / 24, c8 = (i8 - m * 24) * 8;
  const float* p = x + (size_t)img_pos(m) * 192 + c8;
  float4 a = *(const float4*)p, b = *(const float4*)(p + 4);
  ushort_t* q = xw + (size_t)m * 192 + c8;
  *(ushort4*)q       = make_ushort4(f2bf(a.x), f2bf(a.y), f2bf(a.z), f2bf(a.w));
  *(ushort4*)(q + 4) = make_ushort4(f2bf(b.x), f2bf(b.y), f2bf(b.z), f2bf(b.w));
}

// ---------------------------------------------------------------------------
// CPB: tab_s[head][e] = 16*sigmoid( relu(REL_TABLE[e] @ w1.T + b1) @ w2.T )
__global__ __launch_bounds__(256) void cpb_kernel(
    const float* __restrict__ w1, const float* __restrict__ b1,
    const float* __restrict__ w2, float* __restrict__ tab_s) {
  int e = blockIdx.x;            // 0..168
  int t = threadIdx.x;           // 0..255
  int i = e / 13, j = e - 13 * (e / 13);
  auto cval = [](int a) -> float {
    float r = (a - 6) * (8.0f / 6.0f);
    float v = log2f(fabsf(r) + 1.f) * (1.f / 3.f);
    return r < 0.f ? -v : v;
  };
  float ci = cval(i), cj = cval(j);
  float h = fmaxf(ci * w1[2 * t] + cj * w1[2 * t + 1] + b1[t], 0.f);
  __shared__ float red[256];
  for (int head = 0; head < 6; ++head) {
    red[t] = h * w2[head * 256 + t];
    __syncthreads();
    for (int st = 128; st > 0; st >>= 1) {
      if (t < st) red[t] += red[t + st];
      __syncthreads();
    }
    if (t == 0) tab_s[head * 169 + e] = 16.f / (1.f + __expf(-red[0]));
    __syncthreads();
  }
}

// ---------------------------------------------------------------------------
// GEMM, tile 128(M) x 192(N), K-step 32, 512 threads = 8 waves (4x2 of
// 32rows x 96cols). acc[2][6]=48 AGPR. Staging+T14 prefetch on t<256 only.
// MODE 0: qkv  MODE 1: fc1(silu)  MODE 2: proj  MODE 3: fp32 out (fc2)
template<int KTOT, int MODE>
__global__ __launch_bounds__(512, 4) void gemm_n192(
    const ushort_t* __restrict__ Ab, const ushort_t* __restrict__ W,
    const float* __restrict__ b0, const float* __restrict__ b1,
    ushort_t* out, float* outf, int NTOT) {
  __shared__ ushort_t Al[128][40];
  __shared__ ushort_t Bl[192][40];
  int t = threadIdx.x;
  int m0 = blockIdx.x * 128, n0 = blockIdx.y * 192;
  int lane = t & 63, wid = t >> 6;        // wid 0..7
  int wm = wid >> 1, wn = wid & 1;        // wm 0..3 (32-row bands), wn 0..1
  int lr = lane & 15, lg = lane >> 4;

  bool stager = (t < 256);
  int arow = (t & 255) >> 1, akoff = (t & 1) << 4;
  const ushort_t* Arowp = Ab + (size_t)(m0 + arow) * KTOT + akoff;
  int colA = akoff ? 4 : 0;
  int bn = (t & 255) >> 2, cB = t & 3;
  const ushort_t* Browp  = W + (size_t)(n0 + bn) * KTOT + (cB << 3);
  const ushort_t* Browp2 = W + (size_t)(n0 + 64 + bn) * KTOT + (cB << 3);
  const ushort_t* Browp3 = W + (size_t)(n0 + 128 + bn) * KTOT + (cB << 3);
  int colB = ((cB & 1) << 4) | ((cB >> 1) << 2);   // {0,16,4,20}

  f32x4 acc[2][6];
#pragma unroll
  for (int a = 0; a < 2; ++a)
#pragma unroll
    for (int b = 0; b < 6; ++b) acc[a][b] = (f32x4){0.f, 0.f, 0.f, 0.f};

  LD16 A01, A23, B0, B1, B2;
  auto LOADREGS = [&](int kt) {
    A01.v = *(const short8*)(Arowp + kt);
    A23.v = *(const short8*)(Arowp + kt + 8);
    B0.v  = *(const short8*)(Browp + kt);
    B1.v  = *(const short8*)(Browp2 + kt);
    B2.v  = *(const short8*)(Browp3 + kt);
  };

  const int NT = KTOT / 32;
  if (stager) LOADREGS(0);
  for (int it = 0; it < NT; ++it) {
    if (stager) {
      ushort_t* Ar = &Al[arow][0];
      *(ushort4*)(Ar + colA +  0) = A01.h[0];
      *(ushort4*)(Ar + colA +  8) = A01.h[1];
      *(ushort4*)(Ar + colA + 16) = A23.h[0];
      *(ushort4*)(Ar + colA + 24) = A23.h[1];
      ushort_t* Br0 = &Bl[bn][0];
      *(ushort4*)(Br0 + colB + 0) = B0.h[0];
      *(ushort4*)(Br0 + colB + 8) = B0.h[1];
      ushort_t* Br1 = &Bl[64 + bn][0];
      *(ushort4*)(Br1 + colB + 0) = B1.h[0];
      *(ushort4*)(Br1 + colB + 8) = B1.h[1];
      ushort_t* Br2 = &Bl[128 + bn][0];
      *(ushort4*)(Br2 + colB + 0) = B2.h[0];
      *(ushort4*)(Br2 + colB + 8) = B2.h[1];
    }
    __syncthreads();
    if (stager && it + 1 < NT) LOADREGS((it + 1) * 32);   // in flight during MFMAs
    short8 af[2], bfv[6];
#pragma unroll
    for (int fm = 0; fm < 2; ++fm)
      af[fm] = *(const short8*)&Al[wm * 32 + fm * 16 + lr][lg * 8];
#pragma unroll
    for (int fn = 0; fn < 6; ++fn)
      bfv[fn] = *(const short8*)&Bl[wn * 96 + fn * 16 + lr][lg * 8];
#pragma unroll
    for (int fm = 0; fm < 2; ++fm)
#pragma unroll
      for (int fn = 0; fn < 6; ++fn)
        acc[fm][fn] = __builtin_amdgcn_mfma_f32_16x16x32_bf16(af[fm], bfv[fn], acc[fm][fn], 0, 0, 0);
    if (it + 1 < NT) __syncthreads();
  }
#pragma unroll
  for (int fm = 0; fm < 2; ++fm) {
#pragma unroll
    for (int fn = 0; fn < 6; ++fn) {
      int col = n0 + wn * 96 + fn * 16 + lr;
      float bias;
      if (MODE == 0) bias = (col < 192) ? b0[col] : ((col < 384) ? 0.f : b1[col - 384]);
      else           bias = b0[col];
#pragma unroll
      for (int r = 0; r < 4; ++r) {
        int row = m0 + wm * 32 + fm * 16 + lg * 4 + r;
        float v = acc[fm][fn][r] + bias;
        if (MODE == 1) v = v / (1.f + __expf(-v));   // silu
        if (MODE == 3) outf[(size_t)row * NTOT + col] = v;
        else           out[(size_t)row * NTOT + col] = f2bf(v);
      }
    }
  }
}

// ---------------------------------------------------------------------------
// Streaming LayerNorm + residual. One wave per row, 4 waves/block.
template<int MODE>
__global__ __launch_bounds__(256) void ln_resid_kernel(
    const ushort_t* __restrict__ pre, const float* __restrict__ residf,
    const ushort_t* __restrict__ residb, const float* __restrict__ gamma,
    const float* __restrict__ beta, ushort_t* __restrict__ outb,
    float* outio) {
  int m = (blockIdx.x * 256 + threadIdx.x) >> 6;   // row
  int lane = threadIdx.x & 63;
  float v0, v1, v2;
  if (MODE == 0) {
    const ushort_t* p = pre + (size_t)m * 192;
    v0 = bf2f(p[lane]); v1 = bf2f(p[lane + 64]); v2 = bf2f(p[lane + 128]);
  } else {
    const float* p = outio + (size_t)m * 192;
    v0 = p[lane]; v1 = p[lane + 64]; v2 = p[lane + 128];
  }
  float s1 = v0 + v1 + v2;
  float s2 = v0 * v0 + v1 * v1 + v2 * v2;
#pragma unroll
  for (int o = 1; o < 64; o <<= 1) {
    s1 += __shfl_xor(s1, o);
    s2 += __shfl_xor(s2, o);
  }
  float mean = s1 * (1.f / 192.f);
  float var  = s2 * (1.f / 192.f) - mean * mean;
  float rstd = rsqrtf(fmaxf(var, 0.f) + 1e-5f);
  float l0 = (v0 - mean) * rstd * gamma[lane]       + beta[lane];
  float l1 = (v1 - mean) * rstd * gamma[lane + 64]  + beta[lane + 64];
  float l2 = (v2 - mean) * rstd * gamma[lane + 128] + beta[lane + 128];
  if (MODE == 0) {
    size_t og = (size_t)img_pos(m) * 192;
    outb[og + lane]       = f2bf(residf[og + lane]       + l0);
    outb[og + lane + 64]  = f2bf(residf[og + lane + 64]  + l1);
    outb[og + lane + 128] = f2bf(residf[og + lane + 128] + l2);
  } else {
    size_t og = (size_t)m * 192;
    outio[og + lane]       = bf2f(residb[og + lane])       + l0;
    outio[og + lane + 64]  = bf2f(residb[og + lane + 64])  + l1;
    outio[og + lane + 128] = bf2f(residb[og + lane + 128]) + l2;
  }
}

// ---------------------------------------------------------------------------
// Attention (MFMA): block = (window, head), 256 threads = 4 waves. (R10 verbatim)
__global__ __launch_bounds__(256) void attn_kernel(
    const ushort_t* __restrict__ qkv, const float* __restrict__ logit_scale,
    const float* __restrict__ tab_s, ushort_t* __restrict__ attn_out) {
  __shared__ ushort_t qs[64][40];
  __shared__ ushort_t ksl[64][40];
  __shared__ ushort_t vsl[32][80];
  __shared__ ushort_t ps[64][80];
  __shared__ float tab_l[169];
  int win = blockIdx.x, head = blockIdx.y;
  int t = threadIdx.x;
  int wi = win & 63;
  int wh0 = (wi >> 3) * 7, ww0 = (wi & 7) * 7;
  size_t base = (size_t)win * 49 * 576 + head * 32;

  for (int u = t; u < 169; u += 256) tab_l[u] = tab_s[head * 169 + u];

  for (int u = t; u < 240; u += 256) {
    int arr = u / 120, v = u - arr * 120;
    int r = 49 + (v >> 3), c4 = (v & 7) << 2;
    ushort_t* p = arr ? &ksl[r][c4] : &qs[r][c4];
    *(ushort4*)p = make_ushort4(0, 0, 0, 0);
  }

  for (int u = t; u < 2048; u += 256) {
    int key = u >> 5, d = u & 31;
    ushort_t val = 0;
    if (key < 49) val = qkv[base + (size_t)key * 576 + 384 + d];
    int kk = key & 31;
    int pc = ((key >> 5) << 5) + 8 * ((kk >> 2) & 3) + 4 * (kk >> 4) + (kk & 3);
    vsl[d][pc] = val;
  }

  float scale = __expf(fminf(logit_scale[head], 4.605170186f));  // ln(100)

  if (t < 196) {
    int r = t >> 2, c = t & 3;
    const ushort_t* qp = qkv + base + (size_t)r * 576 + c * 8;
    ushort4 qa = *(const ushort4*)qp,         qb = *(const ushort4*)(qp + 4);
    ushort4 ka = *(const ushort4*)(qp + 192), kb = *(const ushort4*)(qp + 196);
    float qf[8] = {bf2f(qa.x), bf2f(qa.y), bf2f(qa.z), bf2f(qa.w),
                   bf2f(qb.x), bf2f(qb.y), bf2f(qb.z), bf2f(qb.w)};
    float kf[8] = {bf2f(ka.x), bf2f(ka.y), bf2f(ka.z), bf2f(ka.w),
                   bf2f(kb.x), bf2f(kb.y), bf2f(kb.z), bf2f(kb.w)};
    float sq = 0.f, sk = 0.f;
#pragma unroll
    for (int d = 0; d < 8; ++d) { sq += qf[d] * qf[d]; sk += kf[d] * kf[d]; }
    sq += __shfl_xor(sq, 1); sq += __shfl_xor(sq, 2);
    sk += __shfl_xor(sk, 1); sk += __shfl_xor(sk, 2);
    float rq = scale / fmaxf(sqrtf(sq), 1e-12f);
    float rk = 1.f   / fmaxf(sqrtf(sk), 1e-12f);
    int c0 = ((c & 1) << 4) | ((c >> 1) << 2);   // {0,16,4,20}
    ushort_t* qd = &qs[r][c0];
    *(ushort4*)(qd + 0) = make_ushort4(f2bf(qf[0]*rq), f2bf(qf[1]*rq), f2bf(qf[2]*rq), f2bf(qf[3]*rq));
    *(ushort4*)(qd + 8) = make_ushort4(f2bf(qf[4]*rq), f2bf(qf[5]*rq), f2bf(qf[6]*rq), f2bf(qf[7]*rq));
    ushort_t* kd = &ksl[r][c0];
    *(ushort4*)(kd + 0) = make_ushort4(f2bf(kf[0]*rk), f2bf(kf[1]*rk), f2bf(kf[2]*rk), f2bf(kf[3]*rk));
    *(ushort4*)(kd + 8) = make_ushort4(f2bf(kf[4]*rk), f2bf(kf[5]*rk), f2bf(kf[6]*rk), f2bf(kf[7]*rk));
  }
  __syncthreads();

  int lane = t & 63, w = t >> 6;
  int lr = lane & 15, lg = lane >> 4;

  short8 aq = *(const short8*)&qs[w * 16 + lr][lg * 8];
  f32x4 acc[4];
#pragma unroll
  for (int fn = 0; fn < 4; ++fn) {
    acc[fn] = (f32x4){0.f, 0.f, 0.f, 0.f};
    short8 bk = *(const short8*)&ksl[fn * 16 + lr][lg * 8];
    acc[fn] = __builtin_amdgcn_mfma_f32_16x16x32_bf16(aq, bk, acc[fn], 0, 0, 0);
  }

  float rsum[4];
#pragma unroll
  for (int r = 0; r < 4; ++r) {
    int row = w * 16 + lg * 4 + r;
    int rd = (row * 9363) >> 16, rm = row - 7 * rd;
    int gr = region3(wh0 + rd) * 3 + region3(ww0 + rm);
    bool rv = row < 49;
    float sv[4];
#pragma unroll
    for (int fn = 0; fn < 4; ++fn) {
      int col = fn * 16 + lr;
      int jd = (col * 9363) >> 16, jm = col - 7 * jd;
      int gj = region3(wh0 + jd) * 3 + region3(ww0 + jm);
      bool cv = rv && (col < 49);
      int idx = cv ? (rd - jd + 6) * 13 + (rm - jm + 6) : 0;
      float s = acc[fn][r] + tab_l[idx] + (gr == gj ? 0.f : -100.f);
      sv[fn] = cv ? s : -1e30f;
    }
    float m = fmaxf(fmaxf(sv[0], sv[1]), fmaxf(sv[2], sv[3]));
#pragma unroll
    for (int o = 1; o < 16; o <<= 1) m = fmaxf(m, __shfl_xor(m, o));
    float sum = 0.f;
#pragma unroll
    for (int fn = 0; fn < 4; ++fn) {
      float e = __expf(sv[fn] - m);
      sum += e;
      int pc = ((fn >> 1) << 5) + 8 * (lr >> 2) + ((fn & 1) << 2) + (lr & 3);
      ps[row][pc] = f2bf(e);
    }
#pragma unroll
    for (int o = 1; o < 16; o <<= 1) sum += __shfl_xor(sum, o);
    rsum[r] = 1.f / sum;
  }
  __syncthreads();

  short8 ap0 = *(const short8*)&ps[w * 16 + lr][lg * 8];
  short8 ap1 = *(const short8*)&ps[w * 16 + lr][32 + lg * 8];
  f32x4 o2[2];
#pragma unroll
  for (int f = 0; f < 2; ++f) {
    o2[f] = (f32x4){0.f, 0.f, 0.f, 0.f};
    short8 bv0 = *(const short8*)&vsl[f * 16 + lr][lg * 8];
    short8 bv1 = *(const short8*)&vsl[f * 16 + lr][32 + lg * 8];
    o2[f] = __builtin_amdgcn_mfma_f32_16x16x32_bf16(ap0, bv0, o2[f], 0, 0, 0);
    o2[f] = __builtin_amdgcn_mfma_f32_16x16x32_bf16(ap1, bv1, o2[f], 0, 0, 0);
  }
#pragma unroll
  for (int f = 0; f < 2; ++f) {
#pragma unroll
    for (int r = 0; r < 4; ++r) {
      int row = w * 16 + lg * 4 + r;
      if (row < 49)
        attn_out[((size_t)win * 49 + row) * 192 + head * 32 + f * 16 + lr] =
            f2bf(o2[f][r] * rsum[r]);
    }
  }
}

// ---------------------------------------------------------------------------
extern "C" void kernel_launch(void* const* d_in, const int* in_sizes, int n_in,
                              void* d_out, int out_size, void* d_ws, size_t ws_size,
                              hipStream_t stream) {
  (void)in_sizes; (void)n_in; (void)out_size; (void)ws_size;
  const float* x    = (const float*)d_in[0];
  const float* qkvw = (const float*)d_in[1];
  const float* qb   = (const float*)d_in[2];
  const float* vb   = (const float*)d_in[3];
  const float* ls   = (const float*)d_in[4];
  const float* cw1  = (const float*)d_in[5];
  const float* cb1  = (const float*)d_in[6];
  const float* cw2  = (const float*)d_in[7];
  const float* pw   = (const float*)d_in[8];
  const float* pb   = (const float*)d_in[9];
  const float* n1g  = (const float*)d_in[10];
  const float* n1b  = (const float*)d_in[11];
  const float* n2g  = (const float*)d_in[12];
  const float* n2b  = (const float*)d_in[13];
  const float* f1w  = (const float*)d_in[14];
  const float* f1b  = (const float*)d_in[15];
  const float* f2w  = (const float*)d_in[16];
  const float* f2b  = (const float*)d_in[17];
  float* out = (float*)d_out;

  char* ws = (char*)d_ws;
  ushort_t* wq_bf = (ushort_t*)ws;                 // 110592
  ushort_t* wp_bf = wq_bf + 110592;                // 36864
  ushort_t* w1_bf = wp_bf + 36864;                 // 147456
  ushort_t* w2_bf = w1_bf + 147456;                // 147456
  float*    tab_s = (float*)(w2_bf + 147456);      // 6*169 floats
  const size_t OFF_BIG = 1 << 20;
  ushort_t* qkv_out = (ushort_t*)(ws + OFF_BIG);
  ushort_t* xw_bf   = (ushort_t*)(ws + OFF_BIG + 115605504);
  ushort_t* attn_o  = (ushort_t*)(ws + OFF_BIG + 115605504);
  ushort_t* x1_bf   = (ushort_t*)(ws + OFF_BIG + 154140672);
  ushort_t* hmid    = (ushort_t*)(ws + OFF_BIG);   // 100352*768 bf16 over R1+R2

  cvt_kernel<<<(110592 + 255) / 256, 256, 0, stream>>>(qkvw, wq_bf, 110592);
  cvt_kernel<<<(36864  + 255) / 256, 256, 0, stream>>>(pw,   wp_bf, 36864);
  cvt_kernel<<<(147456 + 255) / 256, 256, 0, stream>>>(f1w,  w1_bf, 147456);
  cvt_kernel<<<(147456 + 255) / 256, 256, 0, stream>>>(f2w,  w2_bf, 147456);
  cpb_kernel<<<169, 256, 0, stream>>>(cw1, cb1, cw2, tab_s);
  gather_cvt_kernel<<<9408, 256, 0, stream>>>(x, xw_bf);

  // qkv
  gemm_n192<192, 0><<<dim3(784, 3), 512, 0, stream>>>(xw_bf, wq_bf, qb, vb, qkv_out, nullptr, 576);
  // attention
  attn_kernel<<<dim3(2048, 6), 256, 0, stream>>>(qkv_out, ls, tab_s, attn_o);
  // proj (pre-LN, in-place over attn_o) + LN1/residual
  gemm_n192<192, 2><<<dim3(784, 1), 512, 0, stream>>>(attn_o, wp_bf, pb, nullptr, attn_o, nullptr, 192);
  ln_resid_kernel<0><<<25088, 256, 0, stream>>>(attn_o, x, nullptr, n1g, n1b, x1_bf, nullptr);
  // fc1 (silu)
  gemm_n192<192, 1><<<dim3(784, 4), 512, 0, stream>>>(x1_bf, w1_bf, f1b, nullptr, hmid, nullptr, 768);
  // fc2 (pre-LN fp32 -> d_out) + LN2/residual in-place
  gemm_n192<768, 3><<<dim3(784, 1), 512, 0, stream>>>(hmid, w2_bf, f2b, nullptr, nullptr, out, 192);
  ln_resid_kernel<1><<<25088, 256, 0, stream>>>(nullptr, nullptr, x1_bf, n2g, n2b, nullptr, out);
}

// Round 14
// 400.370 us; speedup vs baseline: 1.2135x; 1.0059x over previous
//
#include <hip/hip_runtime.h>

// ============================================================================
// Swin V2 block, round 14 = R13 base (402us best) + persistent-A GEMM for
// K=192 GEMMs: full 128x192 A tile staged in LDS ONCE (slot-permuted),
// N-chunks of 192 looped inside the block (qkv 3, fc1 4, proj 1) -> A
// fetched from HBM exactly once (R13: FETCH=2x A from per-y-slab re-reads;
// dur == bytes/2.7TB/s -> traffic-bound).
// LDS 66.5KB -> 2 blocks/CU x 8 waves (50% cap, same as R13). fc2 (K=768)
// keeps the R13 512-thread path.
// MFMA layout (HW-verified): A row=lane%16, slot=lane/16*8..+7;
// C/D col=lane%16, row=4*(lane/16)+reg. slot(k)=8*((k%16)/4)+4*(k/16)+k%4;
// 8-chunk j -> base b4=((j&1)<<4)|((j>>1)<<2) within 32-block (elems 0-3
// at b4, 4-7 at b4+8).
// ============================================================================

typedef unsigned short ushort_t;
using f32x4  = __attribute__((ext_vector_type(4))) float;
using short8 = __attribute__((ext_vector_type(8))) short;
union LD16 { short8 v; ushort4 h[2]; };

__device__ __forceinline__ ushort_t f2bf(float f) {
  union { float f; unsigned u; } v; v.f = f;
  unsigned r = v.u + 0x7fffu + ((v.u >> 16) & 1u);
  return (ushort_t)(r >> 16);
}
__device__ __forceinline__ float bf2f(ushort_t u) {
  union { unsigned u; float f; } v; v.u = ((unsigned)u) << 16;
  return v.f;
}

// windowed-token index m -> image row index (same map for gather and scatter)
__device__ __forceinline__ int img_pos(int m) {
  int win = m / 49, n = m - win * 49;
  int b = win >> 6, wi = win & 63;
  int nd = n / 7, nm = n - nd * 7;
  int hs = (wi >> 3) * 7 + nd;
  int ws = (wi & 7) * 7 + nm;
  int h = hs + 3; if (h >= 56) h -= 56;
  int w = ws + 3; if (w >= 56) w -= 56;
  return b * 3136 + h * 56 + w;
}

__device__ __forceinline__ int region3(int a) { return a < 49 ? 0 : (a < 53 ? 1 : 2); }

// ---------------------------------------------------------------------------
__global__ void cvt_kernel(const float* __restrict__ in, ushort_t* __restrict__ out, int n) {
  int i = blockIdx.x * 256 + threadIdx.x;
  if (i < n) out[i] = f2bf(in[i]);
}

// gather shifted-window rows + convert to bf16: xw[m][c] = bf16(x[img_pos(m)][c])
__global__ __launch_bounds__(256) void gather_cvt_kernel(
    const float* __restrict__ x, ushort_t* __restrict__ xw) {
  int i8 = blockIdx.x * 256 + threadIdx.x;      // 100352*24 tasks of 8 elems
  int m = i8 / 24, c8 = (i8 - m * 24) * 8;
  const float* p = x + (size_t)img_pos(m) * 192 + c8;
  float4 a = *(const float4*)p, b = *(const float4*)(p + 4);
  ushort_t* q = xw + (size_t)m * 192 + c8;
  *(ushort4*)q       = make_ushort4(f2bf(a.x), f2bf(a.y), f2bf(a.z), f2bf(a.w));
  *(ushort4*)(q + 4) = make_ushort4(f2bf(b.x), f2bf(b.y), f2bf(b.z), f2bf(b.w));
}

// ---------------------------------------------------------------------------
// CPB: tab_s[head][e] = 16*sigmoid( relu(REL_TABLE[e] @ w1.T + b1) @ w2.T )
__global__ __launch_bounds__(256) void cpb_kernel(
    const float* __restrict__ w1, const float* __restrict__ b1,
    const float* __restrict__ w2, float* __restrict__ tab_s) {
  int e = blockIdx.x;            // 0..168
  int t = threadIdx.x;           // 0..255
  int i = e / 13, j = e - 13 * (e / 13);
  auto cval = [](int a) -> float {
    float r = (a - 6) * (8.0f / 6.0f);
    float v = log2f(fabsf(r) + 1.f) * (1.f / 3.f);
    return r < 0.f ? -v : v;
  };
  float ci = cval(i), cj = cval(j);
  float h = fmaxf(ci * w1[2 * t] + cj * w1[2 * t + 1] + b1[t], 0.f);
  __shared__ float red[256];
  for (int head = 0; head < 6; ++head) {
    red[t] = h * w2[head * 256 + t];
    __syncthreads();
    for (int st = 128; st > 0; st >>= 1) {
      if (t < st) red[t] += red[t + st];
      __syncthreads();
    }
    if (t == 0) tab_s[head * 169 + e] = 16.f / (1.f + __expf(-red[0]));
    __syncthreads();
  }
}

// ---------------------------------------------------------------------------
// Persistent-A GEMM (K=192): A tile 128x192 staged in LDS once (slot-perm),
// NCHUNK n-chunks of 192 looped in-block, B staged per K-step (T14 prefetch).
// 512 threads = 8 waves (4x2 of 32x96). acc[2][6].
// MODE 0: qkv  MODE 1: fc1(silu)  MODE 2: proj
template<int NCHUNK, int MODE>
__global__ __launch_bounds__(512, 4) void gemm_persistA(
    const ushort_t* __restrict__ Ab, const ushort_t* __restrict__ W,
    const float* __restrict__ b0, const float* __restrict__ b1,
    ushort_t* __restrict__ out, int NTOT) {
  __shared__ ushort_t Al[128][200];
  __shared__ ushort_t Bl[192][40];
  int t = threadIdx.x;
  int m0 = blockIdx.x * 128;
  int lane = t & 63, wid = t >> 6;
  int wm = wid >> 1, wn = wid & 1;
  int lr = lane & 15, lg = lane >> 4;

  // stage full A tile, slot-permuted: 3072 8-elem chunks over 512 threads
#pragma unroll
  for (int s = 0; s < 6; ++s) {
    int task = t + (s << 9);
    int row = task / 24, j = task - row * 24;
    int blk = (j >> 2) << 5, jj = j & 3;
    int b4 = ((jj & 1) << 4) | ((jj >> 1) << 2);
    LD16 v; v.v = *(const short8*)(Ab + (size_t)(m0 + row) * 192 + j * 8);
    *(ushort4*)&Al[row][blk + b4]     = v.h[0];
    *(ushort4*)&Al[row][blk + b4 + 8] = v.h[1];
  }

  bool stager = (t < 256);
  int bn = (t & 255) >> 2, cB = t & 3;
  int colB = ((cB & 1) << 4) | ((cB >> 1) << 2);   // {0,16,4,20}

  for (int c = 0; c < NCHUNK; ++c) {
    int n0 = c * 192;
    const ushort_t* Browp  = W + (size_t)(n0 + bn) * 192 + (cB << 3);
    const ushort_t* Browp2 = W + (size_t)(n0 + 64 + bn) * 192 + (cB << 3);
    const ushort_t* Browp3 = W + (size_t)(n0 + 128 + bn) * 192 + (cB << 3);
    LD16 B0, B1, B2;
    auto LOADB = [&](int kt) {
      B0.v = *(const short8*)(Browp + kt);
      B1.v = *(const short8*)(Browp2 + kt);
      B2.v = *(const short8*)(Browp3 + kt);
    };

    f32x4 acc[2][6];
#pragma unroll
    for (int a = 0; a < 2; ++a)
#pragma unroll
      for (int b = 0; b < 6; ++b) acc[a][b] = (f32x4){0.f, 0.f, 0.f, 0.f};

    if (stager) LOADB(0);
    for (int it = 0; it < 6; ++it) {
      if (stager) {
        ushort_t* Br0 = &Bl[bn][0];
        *(ushort4*)(Br0 + colB + 0) = B0.h[0];
        *(ushort4*)(Br0 + colB + 8) = B0.h[1];
        ushort_t* Br1 = &Bl[64 + bn][0];
        *(ushort4*)(Br1 + colB + 0) = B1.h[0];
        *(ushort4*)(Br1 + colB + 8) = B1.h[1];
        ushort_t* Br2 = &Bl[128 + bn][0];
        *(ushort4*)(Br2 + colB + 0) = B2.h[0];
        *(ushort4*)(Br2 + colB + 8) = B2.h[1];
      }
      __syncthreads();   // (it==0,c==0) also covers A staging
      if (stager && it + 1 < 6) LOADB((it + 1) * 32);   // in flight during MFMAs
      short8 af[2], bfv[6];
#pragma unroll
      for (int fm = 0; fm < 2; ++fm)
        af[fm] = *(const short8*)&Al[wm * 32 + fm * 16 + lr][it * 32 + lg * 8];
#pragma unroll
      for (int fn = 0; fn < 6; ++fn)
        bfv[fn] = *(const short8*)&Bl[wn * 96 + fn * 16 + lr][lg * 8];
#pragma unroll
      for (int fm = 0; fm < 2; ++fm)
#pragma unroll
        for (int fn = 0; fn < 6; ++fn)
          acc[fm][fn] = __builtin_amdgcn_mfma_f32_16x16x32_bf16(af[fm], bfv[fn], acc[fm][fn], 0, 0, 0);
      __syncthreads();   // Bl reads done before next it/chunk rewrites
    }

#pragma unroll
    for (int fm = 0; fm < 2; ++fm) {
#pragma unroll
      for (int fn = 0; fn < 6; ++fn) {
        int col = n0 + wn * 96 + fn * 16 + lr;
        float bias;
        if (MODE == 0) bias = (col < 192) ? b0[col] : ((col < 384) ? 0.f : b1[col - 384]);
        else           bias = b0[col];
#pragma unroll
        for (int r = 0; r < 4; ++r) {
          int row = m0 + wm * 32 + fm * 16 + lg * 4 + r;
          float v = acc[fm][fn][r] + bias;
          if (MODE == 1) v = v / (1.f + __expf(-v));   // silu
          out[(size_t)row * NTOT + col] = f2bf(v);
        }
      }
    }
  }
}

// ---------------------------------------------------------------------------
// fc2 GEMM (K=768): R13 512-thread path, T14 reg prefetch, fp32 out.
__global__ __launch_bounds__(512, 4) void gemm_fc2(
    const ushort_t* __restrict__ Ab, const ushort_t* __restrict__ W,
    const float* __restrict__ b0, float* __restrict__ outf) {
  const int KTOT = 768, NTOT = 192;
  __shared__ ushort_t Al[128][40];
  __shared__ ushort_t Bl[192][40];
  int t = threadIdx.x;
  int m0 = blockIdx.x * 128;
  int lane = t & 63, wid = t >> 6;
  int wm = wid >> 1, wn = wid & 1;
  int lr = lane & 15, lg = lane >> 4;

  bool stager = (t < 256);
  int arow = (t & 255) >> 1, akoff = (t & 1) << 4;
  const ushort_t* Arowp = Ab + (size_t)(m0 + arow) * KTOT + akoff;
  int colA = akoff ? 4 : 0;
  int bn = (t & 255) >> 2, cB = t & 3;
  const ushort_t* Browp  = W + (size_t)(bn) * KTOT + (cB << 3);
  const ushort_t* Browp2 = W + (size_t)(64 + bn) * KTOT + (cB << 3);
  const ushort_t* Browp3 = W + (size_t)(128 + bn) * KTOT + (cB << 3);
  int colB = ((cB & 1) << 4) | ((cB >> 1) << 2);

  f32x4 acc[2][6];
#pragma unroll
  for (int a = 0; a < 2; ++a)
#pragma unroll
    for (int b = 0; b < 6; ++b) acc[a][b] = (f32x4){0.f, 0.f, 0.f, 0.f};

  LD16 A01, A23, B0, B1, B2;
  auto LOADREGS = [&](int kt) {
    A01.v = *(const short8*)(Arowp + kt);
    A23.v = *(const short8*)(Arowp + kt + 8);
    B0.v  = *(const short8*)(Browp + kt);
    B1.v  = *(const short8*)(Browp2 + kt);
    B2.v  = *(const short8*)(Browp3 + kt);
  };

  const int NT = KTOT / 32;
  if (stager) LOADREGS(0);
  for (int it = 0; it < NT; ++it) {
    if (stager) {
      ushort_t* Ar = &Al[arow][0];
      *(ushort4*)(Ar + colA +  0) = A01.h[0];
      *(ushort4*)(Ar + colA +  8) = A01.h[1];
      *(ushort4*)(Ar + colA + 16) = A23.h[0];
      *(ushort4*)(Ar + colA + 24) = A23.h[1];
      ushort_t* Br0 = &Bl[bn][0];
      *(ushort4*)(Br0 + colB + 0) = B0.h[0];
      *(ushort4*)(Br0 + colB + 8) = B0.h[1];
      ushort_t* Br1 = &Bl[64 + bn][0];
      *(ushort4*)(Br1 + colB + 0) = B1.h[0];
      *(ushort4*)(Br1 + colB + 8) = B1.h[1];
      ushort_t* Br2 = &Bl[128 + bn][0];
      *(ushort4*)(Br2 + colB + 0) = B2.h[0];
      *(ushort4*)(Br2 + colB + 8) = B2.h[1];
    }
    __syncthreads();
    if (stager && it + 1 < NT) LOADREGS((it + 1) * 32);
    short8 af[2], bfv[6];
#pragma unroll
    for (int fm = 0; fm < 2; ++fm)
      af[fm] = *(const short8*)&Al[wm * 32 + fm * 16 + lr][lg * 8];
#pragma unroll
    for (int fn = 0; fn < 6; ++fn)
      bfv[fn] = *(const short8*)&Bl[wn * 96 + fn * 16 + lr][lg * 8];
#pragma unroll
    for (int fm = 0; fm < 2; ++fm)
#pragma unroll
      for (int fn = 0; fn < 6; ++fn)
        acc[fm][fn] = __builtin_amdgcn_mfma_f32_16x16x32_bf16(af[fm], bfv[fn], acc[fm][fn], 0, 0, 0);
    if (it + 1 < NT) __syncthreads();
  }
#pragma unroll
  for (int fm = 0; fm < 2; ++fm) {
#pragma unroll
    for (int fn = 0; fn < 6; ++fn) {
      int col = wn * 96 + fn * 16 + lr;
      float bias = b0[col];
#pragma unroll
      for (int r = 0; r < 4; ++r) {
        int row = m0 + wm * 32 + fm * 16 + lg * 4 + r;
        outf[(size_t)row * NTOT + col] = acc[fm][fn][r] + bias;
      }
    }
  }
}

// ---------------------------------------------------------------------------
// Streaming LayerNorm + residual. One wave per row, 4 waves/block.
template<int MODE>
__global__ __launch_bounds__(256) void ln_resid_kernel(
    const ushort_t* __restrict__ pre, const float* __restrict__ residf,
    const ushort_t* __restrict__ residb, const float* __restrict__ gamma,
    const float* __restrict__ beta, ushort_t* __restrict__ outb,
    float* outio) {
  int m = (blockIdx.x * 256 + threadIdx.x) >> 6;   // row
  int lane = threadIdx.x & 63;
  float v0, v1, v2;
  if (MODE == 0) {
    const ushort_t* p = pre + (size_t)m * 192;
    v0 = bf2f(p[lane]); v1 = bf2f(p[lane + 64]); v2 = bf2f(p[lane + 128]);
  } else {
    const float* p = outio + (size_t)m * 192;
    v0 = p[lane]; v1 = p[lane + 64]; v2 = p[lane + 128];
  }
  float s1 = v0 + v1 + v2;
  float s2 = v0 * v0 + v1 * v1 + v2 * v2;
#pragma unroll
  for (int o = 1; o < 64; o <<= 1) {
    s1 += __shfl_xor(s1, o);
    s2 += __shfl_xor(s2, o);
  }
  float mean = s1 * (1.f / 192.f);
  float var  = s2 * (1.f / 192.f) - mean * mean;
  float rstd = rsqrtf(fmaxf(var, 0.f) + 1e-5f);
  float l0 = (v0 - mean) * rstd * gamma[lane]       + beta[lane];
  float l1 = (v1 - mean) * rstd * gamma[lane + 64]  + beta[lane + 64];
  float l2 = (v2 - mean) * rstd * gamma[lane + 128] + beta[lane + 128];
  if (MODE == 0) {
    size_t og = (size_t)img_pos(m) * 192;
    outb[og + lane]       = f2bf(residf[og + lane]       + l0);
    outb[og + lane + 64]  = f2bf(residf[og + lane + 64]  + l1);
    outb[og + lane + 128] = f2bf(residf[og + lane + 128] + l2);
  } else {
    size_t og = (size_t)m * 192;
    outio[og + lane]       = bf2f(residb[og + lane])       + l0;
    outio[og + lane + 64]  = bf2f(residb[og + lane + 64])  + l1;
    outio[og + lane + 128] = bf2f(residb[og + lane + 128]) + l2;
  }
}

// ---------------------------------------------------------------------------
// Attention (MFMA): block = (window, head), 256 threads = 4 waves. (R13 verbatim)
__global__ __launch_bounds__(256) void attn_kernel(
    const ushort_t* __restrict__ qkv, const float* __restrict__ logit_scale,
    const float* __restrict__ tab_s, ushort_t* __restrict__ attn_out) {
  __shared__ ushort_t qs[64][40];
  __shared__ ushort_t ksl[64][40];
  __shared__ ushort_t vsl[32][80];
  __shared__ ushort_t ps[64][80];
  __shared__ float tab_l[169];
  int win = blockIdx.x, head = blockIdx.y;
  int t = threadIdx.x;
  int wi = win & 63;
  int wh0 = (wi >> 3) * 7, ww0 = (wi & 7) * 7;
  size_t base = (size_t)win * 49 * 576 + head * 32;

  for (int u = t; u < 169; u += 256) tab_l[u] = tab_s[head * 169 + u];

  for (int u = t; u < 240; u += 256) {
    int arr = u / 120, v = u - arr * 120;
    int r = 49 + (v >> 3), c4 = (v & 7) << 2;
    ushort_t* p = arr ? &ksl[r][c4] : &qs[r][c4];
    *(ushort4*)p = make_ushort4(0, 0, 0, 0);
  }

  for (int u = t; u < 2048; u += 256) {
    int key = u >> 5, d = u & 31;
    ushort_t val = 0;
    if (key < 49) val = qkv[base + (size_t)key * 576 + 384 + d];
    int kk = key & 31;
    int pc = ((key >> 5) << 5) + 8 * ((kk >> 2) & 3) + 4 * (kk >> 4) + (kk & 3);
    vsl[d][pc] = val;
  }

  float scale = __expf(fminf(logit_scale[head], 4.605170186f));  // ln(100)

  if (t < 196) {
    int r = t >> 2, c = t & 3;
    const ushort_t* qp = qkv + base + (size_t)r * 576 + c * 8;
    ushort4 qa = *(const ushort4*)qp,         qb = *(const ushort4*)(qp + 4);
    ushort4 ka = *(const ushort4*)(qp + 192), kb = *(const ushort4*)(qp + 196);
    float qf[8] = {bf2f(qa.x), bf2f(qa.y), bf2f(qa.z), bf2f(qa.w),
                   bf2f(qb.x), bf2f(qb.y), bf2f(qb.z), bf2f(qb.w)};
    float kf[8] = {bf2f(ka.x), bf2f(ka.y), bf2f(ka.z), bf2f(ka.w),
                   bf2f(kb.x), bf2f(kb.y), bf2f(kb.z), bf2f(kb.w)};
    float sq = 0.f, sk = 0.f;
#pragma unroll
    for (int d = 0; d < 8; ++d) { sq += qf[d] * qf[d]; sk += kf[d] * kf[d]; }
    sq += __shfl_xor(sq, 1); sq += __shfl_xor(sq, 2);
    sk += __shfl_xor(sk, 1); sk += __shfl_xor(sk, 2);
    float rq = scale / fmaxf(sqrtf(sq), 1e-12f);
    float rk = 1.f   / fmaxf(sqrtf(sk), 1e-12f);
    int c0 = ((c & 1) << 4) | ((c >> 1) << 2);   // {0,16,4,20}
    ushort_t* qd = &qs[r][c0];
    *(ushort4*)(qd + 0) = make_ushort4(f2bf(qf[0]*rq), f2bf(qf[1]*rq), f2bf(qf[2]*rq), f2bf(qf[3]*rq));
    *(ushort4*)(qd + 8) = make_ushort4(f2bf(qf[4]*rq), f2bf(qf[5]*rq), f2bf(qf[6]*rq), f2bf(qf[7]*rq));
    ushort_t* kd = &ksl[r][c0];
    *(ushort4*)(kd + 0) = make_ushort4(f2bf(kf[0]*rk), f2bf(kf[1]*rk), f2bf(kf[2]*rk), f2bf(kf[3]*rk));
    *(ushort4*)(kd + 8) = make_ushort4(f2bf(kf[4]*rk), f2bf(kf[5]*rk), f2bf(kf[6]*rk), f2bf(kf[7]*rk));
  }
  __syncthreads();

  int lane = t & 63, w = t >> 6;
  int lr = lane & 15, lg = lane >> 4;

  short8 aq = *(const short8*)&qs[w * 16 + lr][lg * 8];
  f32x4 acc[4];
#pragma unroll
  for (int fn = 0; fn < 4; ++fn) {
    acc[fn] = (f32x4){0.f, 0.f, 0.f, 0.f};
    short8 bk = *(const short8*)&ksl[fn * 16 + lr][lg * 8];
    acc[fn] = __builtin_amdgcn_mfma_f32_16x16x32_bf16(aq, bk, acc[fn], 0, 0, 0);
  }

  float rsum[4];
#pragma unroll
  for (int r = 0; r < 4; ++r) {
    int row = w * 16 + lg * 4 + r;
    int rd = (row * 9363) >> 16, rm = row - 7 * rd;
    int gr = region3(wh0 + rd) * 3 + region3(ww0 + rm);
    bool rv = row < 49;
    float sv[4];
#pragma unroll
    for (int fn = 0; fn < 4; ++fn) {
      int col = fn * 16 + lr;
      int jd = (col * 9363) >> 16, jm = col - 7 * jd;
      int gj = region3(wh0 + jd) * 3 + region3(ww0 + jm);
      bool cv = rv && (col < 49);
      int idx = cv ? (rd - jd + 6) * 13 + (rm - jm + 6) : 0;
      float s = acc[fn][r] + tab_l[idx] + (gr == gj ? 0.f : -100.f);
      sv[fn] = cv ? s : -1e30f;
    }
    float m = fmaxf(fmaxf(sv[0], sv[1]), fmaxf(sv[2], sv[3]));
#pragma unroll
    for (int o = 1; o < 16; o <<= 1) m = fmaxf(m, __shfl_xor(m, o));
    float sum = 0.f;
#pragma unroll
    for (int fn = 0; fn < 4; ++fn) {
      float e = __expf(sv[fn] - m);
      sum += e;
      int pc = ((fn >> 1) << 5) + 8 * (lr >> 2) + ((fn & 1) << 2) + (lr & 3);
      ps[row][pc] = f2bf(e);
    }
#pragma unroll
    for (int o = 1; o < 16; o <<= 1) sum += __shfl_xor(sum, o);
    rsum[r] = 1.f / sum;
  }
  __syncthreads();

  short8 ap0 = *(const short8*)&ps[w * 16 + lr][lg * 8];
  short8 ap1 = *(const short8*)&ps[w * 16 + lr][32 + lg * 8];
  f32x4 o2[2];
#pragma unroll
  for (int f = 0; f < 2; ++f) {
    o2[f] = (f32x4){0.f, 0.f, 0.f, 0.f};
    short8 bv0 = *(const short8*)&vsl[f * 16 + lr][lg * 8];
    short8 bv1 = *(const short8*)&vsl[f * 16 + lr][32 + lg * 8];
    o2[f] = __builtin_amdgcn_mfma_f32_16x16x32_bf16(ap0, bv0, o2[f], 0, 0, 0);
    o2[f] = __builtin_amdgcn_mfma_f32_16x16x32_bf16(ap1, bv1, o2[f], 0, 0, 0);
  }
#pragma unroll
  for (int f = 0; f < 2; ++f) {
#pragma unroll
    for (int r = 0; r < 4; ++r) {
      int row = w * 16 + lg * 4 + r;
      if (row < 49)
        attn_out[((size_t)win * 49 + row) * 192 + head * 32 + f * 16 + lr] =
            f2bf(o2[f][r] * rsum[r]);
    }
  }
}

// ---------------------------------------------------------------------------
extern "C" void kernel_launch(void* const* d_in, const int* in_sizes, int n_in,
                              void* d_out, int out_size, void* d_ws, size_t ws_size,
                              hipStream_t stream) {
  (void)in_sizes; (void)n_in; (void)out_size; (void)ws_size;
  const float* x    = (const float*)d_in[0];
  const float* qkvw = (const float*)d_in[1];
  const float* qb   = (const float*)d_in[2];
  const float* vb   = (const float*)d_in[3];
  const float* ls   = (const float*)d_in[4];
  const float* cw1  = (const float*)d_in[5];
  const float* cb1  = (const float*)d_in[6];
  const float* cw2  = (const float*)d_in[7];
  const float* pw   = (const float*)d_in[8];
  const float* pb   = (const float*)d_in[9];
  const float* n1g  = (const float*)d_in[10];
  const float* n1b  = (const float*)d_in[11];
  const float* n2g  = (const float*)d_in[12];
  const float* n2b  = (const float*)d_in[13];
  const float* f1w  = (const float*)d_in[14];
  const float* f1b  = (const float*)d_in[15];
  const float* f2w  = (const float*)d_in[16];
  const float* f2b  = (const float*)d_in[17];
  float* out = (float*)d_out;

  char* ws = (char*)d_ws;
  ushort_t* wq_bf = (ushort_t*)ws;                 // 110592
  ushort_t* wp_bf = wq_bf + 110592;                // 36864
  ushort_t* w1_bf = wp_bf + 36864;                 // 147456
  ushort_t* w2_bf = w1_bf + 147456;                // 147456
  float*    tab_s = (float*)(w2_bf + 147456);      // 6*169 floats
  const size_t OFF_BIG = 1 << 20;
  ushort_t* qkv_out = (ushort_t*)(ws + OFF_BIG);
  ushort_t* xw_bf   = (ushort_t*)(ws + OFF_BIG + 115605504);
  ushort_t* attn_o  = (ushort_t*)(ws + OFF_BIG + 115605504);
  ushort_t* x1_bf   = (ushort_t*)(ws + OFF_BIG + 154140672);
  ushort_t* hmid    = (ushort_t*)(ws + OFF_BIG);   // 100352*768 bf16 over R1+R2

  cvt_kernel<<<(110592 + 255) / 256, 256, 0, stream>>>(qkvw, wq_bf, 110592);
  cvt_kernel<<<(36864  + 255) / 256, 256, 0, stream>>>(pw,   wp_bf, 36864);
  cvt_kernel<<<(147456 + 255) / 256, 256, 0, stream>>>(f1w,  w1_bf, 147456);
  cvt_kernel<<<(147456 + 255) / 256, 256, 0, stream>>>(f2w,  w2_bf, 147456);
  cpb_kernel<<<169, 256, 0, stream>>>(cw1, cb1, cw2, tab_s);
  gather_cvt_kernel<<<9408, 256, 0, stream>>>(x, xw_bf);

  // qkv (A staged once, 3 n-chunks)
  gemm_persistA<3, 0><<<784, 512, 0, stream>>>(xw_bf, wq_bf, qb, vb, qkv_out, 576);
  // attention
  attn_kernel<<<dim3(2048, 6), 256, 0, stream>>>(qkv_out, ls, tab_s, attn_o);
  // proj (pre-LN, in-place over attn_o) + LN1/residual
  gemm_persistA<1, 2><<<784, 512, 0, stream>>>(attn_o, wp_bf, pb, nullptr, attn_o, 192);
  ln_resid_kernel<0><<<25088, 256, 0, stream>>>(attn_o, x, nullptr, n1g, n1b, x1_bf, nullptr);
  // fc1 (A staged once, 4 n-chunks, silu)
  gemm_persistA<4, 1><<<784, 512, 0, stream>>>(x1_bf, w1_bf, f1b, nullptr, hmid, 768);
  // fc2 (pre-LN fp32 -> d_out) + LN2/residual in-place
  gemm_fc2<<<784, 512, 0, stream>>>(hmid, w2_bf, f2b, out);
  ln_resid_kernel<1><<<25088, 256, 0, stream>>>(nullptr, nullptr, x1_bf, n2g, n2b, nullptr, out);
}